// Round 26
// baseline (605.918 us; speedup 1.0000x reference)
//
#include <hip/hip_runtime.h>
#include <math.h>

#define BB 8
#define NN 2048
#define DD 256
#define KNN 8
#define NPTS (BB*NN)        // 16384
#define NEDGE (NPTS*KNN)    // 131072
#define BN_EPS 1e-5f
#define NSH 64              // shadow copies for BN stats accumulation
#define PSH 32              // shadow copies for pooled max/min

// ---- workspace layout (float offsets) ----
#define OFF_X      0
#define OFF_FEAT   (OFF_X + NPTS*DD)          // region holds feathi+featlo (ushort), pdg/pjg overlay
#define OFF_STATS  (OFF_FEAT + NPTS*3*DD)     // NSH x 1024
#define OFF_PMAXS  (OFF_STATS + NSH*1024)     // PSH x BB x 256
#define OFF_SQ     (OFF_PMAXS + PSH*BB*DD)    // NPTS
#define OFF_PMINS  (OFF_SQ + NPTS)            // PSH x BB x 256
#define OFF_IDX    (OFF_PMINS + PSH*BB*DD)
#define OFF_U      (OFF_IDX + NEDGE)
#define OFF_V      (OFF_U + NPTS*DD)
#define OFF_W2BF   (OFF_V + NPTS*DD)          // 256x256 ushort
#define OFF_BIASP  (OFF_W2BF + 32768)
#define OFF_XHI    (OFF_BIASP + DD)           // NPTS x 256 ushort
#define OFF_XLO    (OFF_XHI + NPTS*DD/2)      // NPTS x 256 ushort
#define OFF_MWH    (OFF_XLO + NPTS*DD/2)      // 256x768 ushort (transposed)
#define OFF_MWL    (OFF_MWH + 98304)
#define OFF_WUH    (OFF_MWL + 98304)          // 4 uv weight tables, 256x256 ushort each
#define OFF_WUL    (OFF_WUH + 32768)
#define OFF_WBH    (OFF_WUL + 32768)
#define OFF_WBL    (OFF_WBH + 32768)

typedef __attribute__((ext_vector_type(8))) short bf16x8;
typedef __attribute__((ext_vector_type(4))) float f32x4;

__device__ __forceinline__ unsigned short f2bf(float f) {
  unsigned int u = __float_as_uint(f);
  u += 0x7FFF + ((u >> 16) & 1);   // round to nearest even
  return (unsigned short)(u >> 16);
}
__device__ __forceinline__ float bf2f(unsigned short h) {
  return __uint_as_float((unsigned int)h << 16);
}

// ---------------- merged prep: featurize (bx<4096) | prep_mw (bx<4864) | prep_uvw.
// All three are mutually independent; merging hides the two small preps inside featurize.
__global__ __launch_bounds__(256) void prepk(
    const int* __restrict__ cls, const float* __restrict__ colors, const float* __restrict__ positions,
    const float* __restrict__ ctab,
    const float* __restrict__ pW1, const float* __restrict__ pb1, const float* __restrict__ pW2, const float* __restrict__ pb2,
    const float* __restrict__ cW1, const float* __restrict__ cb1, const float* __restrict__ cW2, const float* __restrict__ cb2,
    unsigned short* __restrict__ feathi, unsigned short* __restrict__ featlo,
    const float* __restrict__ mW,
    unsigned short* __restrict__ mwh, unsigned short* __restrict__ mwl,
    const float* __restrict__ gW1,
    unsigned short* __restrict__ Wuh, unsigned short* __restrict__ Wul,
    unsigned short* __restrict__ Wbh, unsigned short* __restrict__ Wbl)
{
  __shared__ float wbuf[4][64];
  int bx = blockIdx.x;
  int tid = threadIdx.x;
  if (bx < 4096) {
    // ---- featurize: wave-per-point, 4 points/block (R24-proven) ----
    int wv = tid >> 6, lane = tid & 63;
    int p = bx*4 + wv;
    if (lane < 32) {
      float c0 = colors[p*3+0], c1 = colors[p*3+1], c2 = colors[p*3+2];
      wbuf[wv][lane] = fmaxf(c0*cW1[lane] + c1*cW1[32+lane] + c2*cW1[64+lane] + cb1[lane], 0.f);
    } else {
      int l = lane - 32;
      float q0 = positions[p*3+0], q1 = positions[p*3+1], q2 = positions[p*3+2];
      wbuf[wv][32+l] = fmaxf(q0*pW1[l] + q1*pW1[32+l] + q2*pW1[64+l] + pb1[l], 0.f);
    }
    __syncthreads();
    int c = lane*4;
    float4 ce4 = *(const float4*)&ctab[(size_t)cls[p]*DD + c];
    float4 col4 = *(const float4*)&cb2[c];
    float4 pos4 = *(const float4*)&pb2[c];
    #pragma unroll
    for (int k = 0; k < 32; k++) {
      float ch = wbuf[wv][k], ph = wbuf[wv][32+k];
      float4 cw = *(const float4*)&cW2[k*DD + c];
      float4 pw = *(const float4*)&pW2[k*DD + c];
      col4.x += ch*cw.x; col4.y += ch*cw.y; col4.z += ch*cw.z; col4.w += ch*cw.w;
      pos4.x += ph*pw.x; pos4.y += ph*pw.y; pos4.z += ph*pw.z; pos4.w += ph*pw.w;
    }
    col4.x = fmaxf(col4.x, 0.f); col4.y = fmaxf(col4.y, 0.f);
    col4.z = fmaxf(col4.z, 0.f); col4.w = fmaxf(col4.w, 0.f);
    pos4.x = fmaxf(pos4.x, 0.f); pos4.y = fmaxf(pos4.y, 0.f);
    pos4.z = fmaxf(pos4.z, 0.f); pos4.w = fmaxf(pos4.w, 0.f);
    float sce  = ce4.x*ce4.x + ce4.y*ce4.y + ce4.z*ce4.z + ce4.w*ce4.w;
    float scol = col4.x*col4.x + col4.y*col4.y + col4.z*col4.z + col4.w*col4.w;
    float spos = pos4.x*pos4.x + pos4.y*pos4.y + pos4.z*pos4.z + pos4.w*pos4.w;
    #pragma unroll
    for (int m = 1; m <= 32; m <<= 1) {
      sce  += __shfl_xor(sce,  m, 64);
      scol += __shfl_xor(scol, m, 64);
      spos += __shfl_xor(spos, m, 64);
    }
    float ice = 1.f / fmaxf(sqrtf(sce),  1e-12f);
    float icl = 1.f / fmaxf(sqrtf(scol), 1e-12f);
    float ips = 1.f / fmaxf(sqrtf(spos), 1e-12f);
    float o[3][4] = {
      {ce4.x*ice,  ce4.y*ice,  ce4.z*ice,  ce4.w*ice},
      {col4.x*icl, col4.y*icl, col4.z*icl, col4.w*icl},
      {pos4.x*ips, pos4.y*ips, pos4.z*ips, pos4.w*ips}
    };
    #pragma unroll
    for (int sgm = 0; sgm < 3; sgm++) {
      unsigned short h[4], l[4];
      #pragma unroll
      for (int cc = 0; cc < 4; cc++) {
        h[cc] = f2bf(o[sgm][cc]);
        l[cc] = f2bf(o[sgm][cc] - bf2f(h[cc]));
      }
      size_t off = (size_t)p*768 + sgm*256 + c;
      *(uint2*)&feathi[off] = make_uint2((unsigned)h[0] | ((unsigned)h[1] << 16),
                                         (unsigned)h[2] | ((unsigned)h[3] << 16));
      *(uint2*)&featlo[off] = make_uint2((unsigned)l[0] | ((unsigned)l[1] << 16),
                                         (unsigned)l[2] | ((unsigned)l[3] << 16));
    }
  } else if (bx < 4096 + 768) {
    // ---- prep_mw: transposed split-bf16 of mW [768][256] -> [256][768] ----
    int k = bx - 4096;
    int n = tid;
    float wgt = mW[(size_t)k*DD + n];
    unsigned short h = f2bf(wgt);
    mwh[(size_t)n*768 + k] = h;
    mwl[(size_t)n*768 + k] = f2bf(wgt - bf2f(h));
  } else {
    // ---- prep_uvw: transposed split-bf16 uv weight tables (R21-proven math) ----
    int k = bx - (4096 + 768);
    int n = tid;
    float t = gW1[(size_t)k*DD + n];
    float b = gW1[(size_t)(k + DD)*DD + n];
    float wu = t - b;
    unsigned short uh = f2bf(wu), bh = f2bf(b);
    Wuh[(size_t)n*DD + k] = uh;
    Wul[(size_t)n*DD + k] = f2bf(wu - bf2f(uh));
    Wbh[(size_t)n*DD + k] = bh;
    Wbl[(size_t)n*DD + k] = f2bf(b - bf2f(bh));
  }
}

// ---------------- merge GEMM via split-bf16 MFMA, col-split x2 (R24-proven; dead x write removed)
__global__ __launch_bounds__(256) void gemm768(
    const unsigned short* __restrict__ feathi, const unsigned short* __restrict__ featlo,
    const unsigned short* __restrict__ mwh, const unsigned short* __restrict__ mwl,
    const float* __restrict__ mb,
    float* __restrict__ sqo,
    unsigned short* __restrict__ xhi, unsigned short* __restrict__ xlo)
{
  __shared__ float wSh[128*18];
  __shared__ float wSl[128*18];
  int tid = threadIdx.x;
  int w = tid >> 6, lane = tid & 63;
  int m = lane & 15, quad = lane >> 4;
  int rowbase = blockIdx.x * 64;
  int colbase = blockIdx.y * 128;
  size_t aoff = (size_t)(rowbase + w*16 + m)*768;
  int srow = tid >> 1;
  int sseg = (tid & 1) * 2;
  f32x4 acc[8];
  #pragma unroll
  for (int t = 0; t < 8; t++) acc[t] = (f32x4){0.f, 0.f, 0.f, 0.f};
  #pragma unroll 1
  for (int c = 0; c < 24; c++) {
    int k0 = c*32 + quad*8;
    bf16x8 ah = *(const bf16x8*)(feathi + aoff + k0);
    bf16x8 al = *(const bf16x8*)(featlo + aoff + k0);
    const float* wrh = (const float*)(mwh + (size_t)(colbase + srow)*768 + c*32);
    const float* wrl = (const float*)(mwl + (size_t)(colbase + srow)*768 + c*32);
    float4 wh0 = *(const float4*)(wrh + sseg*4);
    float4 wh1 = *(const float4*)(wrh + (sseg+1)*4);
    float4 wl0 = *(const float4*)(wrl + sseg*4);
    float4 wl1 = *(const float4*)(wrl + (sseg+1)*4);
    __syncthreads();
    *(float4*)&wSh[srow*18 + sseg*4]     = wh0;
    *(float4*)&wSh[srow*18 + (sseg+1)*4] = wh1;
    *(float4*)&wSl[srow*18 + sseg*4]     = wl0;
    *(float4*)&wSl[srow*18 + (sseg+1)*4] = wl1;
    __syncthreads();
    #pragma unroll
    for (int nt = 0; nt < 8; nt++) {
      bf16x8 bh = *(const bf16x8*)&wSh[(nt*16 + m)*18 + quad*4];
      bf16x8 bl = *(const bf16x8*)&wSl[(nt*16 + m)*18 + quad*4];
      acc[nt] = __builtin_amdgcn_mfma_f32_16x16x32_bf16(ah, bh, acc[nt], 0, 0, 0);
      acc[nt] = __builtin_amdgcn_mfma_f32_16x16x32_bf16(ah, bl, acc[nt], 0, 0, 0);
      acc[nt] = __builtin_amdgcn_mfma_f32_16x16x32_bf16(al, bh, acc[nt], 0, 0, 0);
    }
  }
  float sqp[4] = {0.f, 0.f, 0.f, 0.f};
  #pragma unroll
  for (int nt = 0; nt < 8; nt++) {
    int col = colbase + nt*16 + m;
    float bp = mb[col];
    #pragma unroll
    for (int r = 0; r < 4; r++) {
      float o = fmaxf(acc[nt][r] + bp, 0.f);
      int row = rowbase + w*16 + quad*4 + r;
      unsigned short h = f2bf(o);
      xhi[(size_t)row*DD + col] = h;
      xlo[(size_t)row*DD + col] = f2bf(o - bf2f(h));
      sqp[r] += o*o;
    }
  }
  #pragma unroll
  for (int r = 0; r < 4; r++) {
    #pragma unroll
    for (int mm = 1; mm <= 8; mm <<= 1) sqp[r] += __shfl_xor(sqp[r], mm, 64);
  }
  if (m == 0) {
    #pragma unroll
    for (int r = 0; r < 4; r++)
      atomicAdd(&sqo[rowbase + w*16 + quad*4 + r], sqp[r]);
  }
}

// ---------------- merged kNN + u/v GEMM, interleaved block dispatch (bx&1):
// both depend only on gemm768; co-residency fills knnk's barrier stalls with
// gemmuv MFMA/staging work. Shared LDS arena = max(knnk 4736, gemmuv 4608) floats.
__global__ __launch_bounds__(256) void knnuv(
    const unsigned short* __restrict__ xhi, const unsigned short* __restrict__ xlo,
    const float* __restrict__ sq,
    float* __restrict__ pdg, int* __restrict__ pjg,
    const unsigned short* __restrict__ Wuh, const unsigned short* __restrict__ Wul,
    const unsigned short* __restrict__ Wbh, const unsigned short* __restrict__ Wbl,
    float* __restrict__ U, float* __restrict__ V)
{
  __shared__ float smem[4736];
  int bx = blockIdx.x;
  int tid = threadIdx.x;
  int w = tid >> 6, lane = tid & 63;
  int m = lane & 15, quad = lane >> 4;
  if ((bx & 1) == 0) {
    // ================= knnk (R20/R23-proven), kid = bx>>1 =================
    int kid = bx >> 1;
    float* jh = smem;                 // 64 rows x 36 floats
    float* jl = smem + 2304;
    float (*dt)[65] = (float(*)[65])smem;
    float* sqI = smem + 4608;
    float* sqJ = smem + 4672;
    int q  = kid & 3;
    int it = (kid >> 2) & 31;
    int bb = kid >> 7;
    int ibase = it * 64;
    const unsigned short* xhb = xhi + (size_t)bb*NN*DD;
    const unsigned short* xlb = xlo + (size_t)bb*NN*DD;
    const float* sqb = sq + (size_t)bb*NN;
    int selrow = tid & 63, selseg = tid >> 6;
    size_t aoff = (size_t)(ibase + w*16 + m)*DD;
    int srow = tid >> 2;
    int sseg = tid & 3;
    bf16x8 ahr[8], alr[8];
    #pragma unroll
    for (int c = 0; c < 8; c++) {
      int k0 = c*32 + quad*8;
      ahr[c] = *(const bf16x8*)(xhb + aoff + k0);
      alr[c] = *(const bf16x8*)(xlb + aoff + k0);
    }
    float bd[8]; int bj[8];
    #pragma unroll
    for (int s = 0; s < 8; s++) { bd[s] = 3.4e38f; bj[s] = 0; }
    if (tid < 64) sqI[tid] = sqb[ibase + tid];
    #pragma unroll 1
    for (int jt = 0; jt < 8; jt++) {
      int jbase = q*512 + jt*64;
      if (tid < 64) sqJ[tid] = sqb[jbase + tid];
      f32x4 acc[4];
      #pragma unroll
      for (int t = 0; t < 4; t++) acc[t] = (f32x4){0.f, 0.f, 0.f, 0.f};
      #pragma unroll
      for (int c2 = 0; c2 < 4; c2++) {
        size_t gb = (size_t)(jbase + srow)*DD + c2*64;
        float4 h0 = *(const float4*)((const float*)(xhb + gb) + sseg*4);
        float4 h1 = *(const float4*)((const float*)(xhb + gb) + (sseg+4)*4);
        float4 l0 = *(const float4*)((const float*)(xlb + gb) + sseg*4);
        float4 l1 = *(const float4*)((const float*)(xlb + gb) + (sseg+4)*4);
        __syncthreads();
        *(float4*)&jh[srow*36 + sseg*4]     = h0;
        *(float4*)&jh[srow*36 + (sseg+4)*4] = h1;
        *(float4*)&jl[srow*36 + sseg*4]     = l0;
        *(float4*)&jl[srow*36 + (sseg+4)*4] = l1;
        __syncthreads();
        #pragma unroll
        for (int kk = 0; kk < 2; kk++) {
          bf16x8 ah = ahr[c2*2 + kk];
          bf16x8 al = alr[c2*2 + kk];
          int lofs = kk*16 + quad*4;
          #pragma unroll
          for (int nt = 0; nt < 4; nt++) {
            int r = nt*16 + m;
            bf16x8 bh = *(const bf16x8*)&jh[r*36 + lofs];
            bf16x8 bl = *(const bf16x8*)&jl[r*36 + lofs];
            acc[nt] = __builtin_amdgcn_mfma_f32_16x16x32_bf16(ah, bh, acc[nt], 0, 0, 0);
            acc[nt] = __builtin_amdgcn_mfma_f32_16x16x32_bf16(ah, bl, acc[nt], 0, 0, 0);
            acc[nt] = __builtin_amdgcn_mfma_f32_16x16x32_bf16(al, bh, acc[nt], 0, 0, 0);
          }
        }
      }
      __syncthreads();
      #pragma unroll
      for (int nt = 0; nt < 4; nt++) {
        int col = nt*16 + m;
        float sj = sqJ[col];
        #pragma unroll
        for (int r = 0; r < 4; r++) {
          int rowl = w*16 + quad*4 + r;
          dt[rowl][col] = sqI[rowl] + sj - 2.f*acc[nt][r];
        }
      }
      __syncthreads();
      int cb = selseg*16;
      #pragma unroll
      for (int s = 0; s < 16; s++) {
        float dv = dt[selrow][cb + s];
        if (dv < bd[7]) {
          bd[7] = dv; bj[7] = jbase + cb + s;
          #pragma unroll
          for (int t = 7; t >= 1; t--) {
            if (bd[t] < bd[t-1]) {
              float td = bd[t]; bd[t] = bd[t-1]; bd[t-1] = td;
              int   tj = bj[t]; bj[t] = bj[t-1]; bj[t-1] = tj;
            }
          }
        }
      }
    }
    __syncthreads();
    float* pdl = &smem[0];
    int*   pjl = (int*)&smem[2048];
    #pragma unroll
    for (int s = 0; s < 8; s++) {
      pdl[tid*8 + s] = bd[s];
      pjl[tid*8 + s] = bj[s];
    }
    __syncthreads();
    if (tid < 64) {
      float md[8]; int mj[8];
      #pragma unroll
      for (int s = 0; s < 8; s++) { md[s] = 3.4e38f; mj[s] = 0; }
      #pragma unroll 1
      for (int g = 0; g < 4; g++) {
        int base = (g*64 + tid)*8;
        #pragma unroll
        for (int s = 0; s < 8; s++) {
          float dv = pdl[base + s];
          if (dv < md[7]) {
            md[7] = dv; mj[7] = pjl[base + s];
            #pragma unroll
            for (int t = 7; t >= 1; t--) {
              if (md[t] < md[t-1]) {
                float td = md[t]; md[t] = md[t-1]; md[t-1] = td;
                int   tj = mj[t]; mj[t] = mj[t-1]; mj[t-1] = tj;
              }
            }
          }
        }
      }
      size_t gbase = ((size_t)(bb*NN + ibase + tid))*32 + (size_t)q*8;
      #pragma unroll
      for (int s = 0; s < 8; s++) {
        pdg[gbase + s] = md[s];
        pjg[gbase + s] = bb*NN + mj[s];
      }
    }
  } else {
    // ================= gemmuv (R25-proven), gid = bx>>1 =================
    int gid = bx >> 1;
    float* wSh = smem;               // 128*18 = 2304
    float* wSl = smem + 2304;        // 128*18 = 2304
    int rowbase = (gid & 255) * 64;
    int yy = gid >> 8;               // 0..3
    int uv = yy >> 1;
    int colbase = (yy & 1) * 128;
    const unsigned short* Wh = uv ? Wbh : Wuh;
    const unsigned short* Wl = uv ? Wbl : Wul;
    float* Out = uv ? V : U;
    size_t aoff = (size_t)(rowbase + w*16 + m)*DD;
    int srow = tid >> 1;
    int sseg = (tid & 1) * 2;
    f32x4 acc[8];
    #pragma unroll
    for (int t = 0; t < 8; t++) acc[t] = (f32x4){0.f, 0.f, 0.f, 0.f};
    #pragma unroll 1
    for (int c = 0; c < 8; c++) {
      int k0 = c*32 + quad*8;
      bf16x8 ah = *(const bf16x8*)(xhi + aoff + k0);
      bf16x8 al = *(const bf16x8*)(xlo + aoff + k0);
      const float* wrh = (const float*)(Wh + (size_t)(colbase + srow)*DD + c*32);
      const float* wrl = (const float*)(Wl + (size_t)(colbase + srow)*DD + c*32);
      float4 wh0 = *(const float4*)(wrh + sseg*4);
      float4 wh1 = *(const float4*)(wrh + (sseg+1)*4);
      float4 wl0 = *(const float4*)(wrl + sseg*4);
      float4 wl1 = *(const float4*)(wrl + (sseg+1)*4);
      __syncthreads();
      *(float4*)&wSh[srow*18 + sseg*4]     = wh0;
      *(float4*)&wSh[srow*18 + (sseg+1)*4] = wh1;
      *(float4*)&wSl[srow*18 + sseg*4]     = wl0;
      *(float4*)&wSl[srow*18 + (sseg+1)*4] = wl1;
      __syncthreads();
      #pragma unroll
      for (int nt = 0; nt < 8; nt++) {
        bf16x8 bh = *(const bf16x8*)&wSh[(nt*16 + m)*18 + quad*4];
        bf16x8 bl = *(const bf16x8*)&wSl[(nt*16 + m)*18 + quad*4];
        acc[nt] = __builtin_amdgcn_mfma_f32_16x16x32_bf16(ah, bh, acc[nt], 0, 0, 0);
        acc[nt] = __builtin_amdgcn_mfma_f32_16x16x32_bf16(ah, bl, acc[nt], 0, 0, 0);
        acc[nt] = __builtin_amdgcn_mfma_f32_16x16x32_bf16(al, bh, acc[nt], 0, 0, 0);
      }
    }
    #pragma unroll
    for (int nt = 0; nt < 8; nt++) {
      int col = colbase + nt*16 + m;
      #pragma unroll
      for (int r = 0; r < 4; r++) {
        int row = rowbase + w*16 + quad*4 + r;
        Out[(size_t)row*DD + col] = acc[nt][r];
      }
    }
  }
}

// ---------------- merge 4 quarter-lists per point -> final 8 neighbor indices
__global__ __launch_bounds__(256) void knnmerge(const float* __restrict__ pdg, const int* __restrict__ pjg,
                                                int* __restrict__ idxg)
{
  int p = blockIdx.x*256 + threadIdx.x;
  float md[8]; int mj[8];
  #pragma unroll
  for (int s = 0; s < 8; s++) { md[s] = 3.4e38f; mj[s] = 0; }
  size_t base = (size_t)p*32;
  #pragma unroll 1
  for (int s = 0; s < 32; s++) {
    float dv = pdg[base + s];
    if (dv < md[7]) {
      md[7] = dv; mj[7] = pjg[base + s];
      #pragma unroll
      for (int t = 7; t >= 1; t--) {
        if (md[t] < md[t-1]) {
          float td = md[t]; md[t] = md[t-1]; md[t-1] = td;
          int   tj = mj[t]; mj[t] = mj[t-1]; mj[t-1] = tj;
        }
      }
    }
  }
  #pragma unroll
  for (int s = 0; s < 8; s++) idxg[(size_t)p*8 + s] = mj[s];
}

// ---------------- BN1 stats: h1 = relu(u_i + v_j + b1), shadow-accumulator atomics
__global__ __launch_bounds__(256) void bn1stats(const float* __restrict__ u, const float* __restrict__ v,
    const int* __restrict__ idxg, const float* __restrict__ b1, float* __restrict__ stats)
{
  __shared__ int jL[128];
  int c = threadIdx.x;
  int n0 = blockIdx.x * 16;
  if (c < 128) jL[c] = idxg[(size_t)n0*8 + c];
  __syncthreads();
  float b1c = b1[c];
  float s = 0.f, s2 = 0.f;
  #pragma unroll 1
  for (int n = 0; n < 16; n++) {
    float uc = u[(size_t)(n0 + n)*DD + c];
    #pragma unroll
    for (int e = 0; e < 8; e++) {
      int j = jL[n*8 + e];
      float h = fmaxf(uc + v[(size_t)j*DD + c] + b1c, 0.f);
      s += h; s2 += h*h;
    }
  }
  int row = blockIdx.x & (NSH - 1);
  atomicAdd(&stats[row*1024 + c], s);
  atomicAdd(&stats[row*1024 + 256 + c], s2);
}

// ---------------- fold BN1 into layer-2 weights; emit TRANSPOSED bf16 weights
__global__ __launch_bounds__(256) void prep2(const float* __restrict__ stats, const float* __restrict__ g1,
    const float* __restrict__ be1, const float* __restrict__ gW2, const float* __restrict__ gb2,
    unsigned short* __restrict__ w2bf, float* __restrict__ biasp)
{
  __shared__ float s1L[256], t1L[256];
  int tid = threadIdx.x;
  const float inv = 1.f / (float)NEDGE;
  float sm = 0.f, sq2 = 0.f;
  #pragma unroll 1
  for (int r = 0; r < NSH; r++) {
    sm  += stats[r*1024 + tid];
    sq2 += stats[r*1024 + 256 + tid];
  }
  float m = sm * inv;
  float var = sq2*inv - m*m;
  float s1 = g1[tid] / sqrtf(var + BN_EPS);
  s1L[tid] = s1; t1L[tid] = be1[tid] - m*s1;
  __syncthreads();
  float bacc = gb2[tid];
  for (int k = 0; k < DD; k++) {
    float w = gW2[k*DD + tid];
    w2bf[(size_t)tid*DD + k] = f2bf(s1L[k]*w);
    bacc += t1L[k]*w;
  }
  biasp[tid] = bacc;
}

// ---------------- edge GEMM via bf16 MFMA, column-split x2 (R23-proven)
__global__ __launch_bounds__(256) void edgek(
    const float* __restrict__ u, const float* __restrict__ v, const int* __restrict__ idxg,
    const float* __restrict__ b1, const unsigned short* __restrict__ w2bf,
    const float* __restrict__ biasp,
    float* __restrict__ pmaxs, float* __restrict__ pmins, float* __restrict__ stats)
{
  __shared__ float wS[128*18];     // 9 KB
  int tid = threadIdx.x;
  int w = tid >> 6, lane = tid & 63;
  int m = lane & 15, quad = lane >> 4;
  int rowbase = blockIdx.x * 64;
  int colbase = blockIdx.y * 128;
  int edge = rowbase + w*16 + m;
  int iu = edge >> 3;
  int jv = idxg[edge];
  const float* urow = u + (size_t)iu*DD;
  const float* vrow = v + (size_t)jv*DD;
  int srow = tid >> 1;
  int sseg = (tid & 1) * 2;
  f32x4 acc[8];
  #pragma unroll
  for (int t = 0; t < 8; t++) acc[t] = (f32x4){0.f, 0.f, 0.f, 0.f};
  #pragma unroll 1
  for (int c = 0; c < 8; c++) {
    int k0 = c*32 + quad*8;
    float4 ua = *(const float4*)(urow + k0);
    float4 ub = *(const float4*)(urow + k0 + 4);
    float4 va = *(const float4*)(vrow + k0);
    float4 vb = *(const float4*)(vrow + k0 + 4);
    float4 ba = *(const float4*)(b1 + k0);
    float4 bb = *(const float4*)(b1 + k0 + 4);
    const float* wrow = (const float*)(w2bf + (size_t)(colbase + srow)*DD + c*32);
    float4 wreg0 = *(const float4*)(wrow + sseg*4);
    float4 wreg1 = *(const float4*)(wrow + (sseg+1)*4);
    float h0 = fmaxf(ua.x+va.x+ba.x, 0.f);
    float h1 = fmaxf(ua.y+va.y+ba.y, 0.f);
    float h2 = fmaxf(ua.z+va.z+ba.z, 0.f);
    float h3 = fmaxf(ua.w+va.w+ba.w, 0.f);
    float h4 = fmaxf(ub.x+vb.x+bb.x, 0.f);
    float h5 = fmaxf(ub.y+vb.y+bb.y, 0.f);
    float h6 = fmaxf(ub.z+vb.z+bb.z, 0.f);
    float h7 = fmaxf(ub.w+vb.w+bb.w, 0.f);
    union { bf16x8 v8; unsigned short s[8]; } af;
    af.s[0] = f2bf(h0); af.s[1] = f2bf(h1); af.s[2] = f2bf(h2); af.s[3] = f2bf(h3);
    af.s[4] = f2bf(h4); af.s[5] = f2bf(h5); af.s[6] = f2bf(h6); af.s[7] = f2bf(h7);
    __syncthreads();
    *(float4*)&wS[srow*18 + sseg*4]     = wreg0;
    *(float4*)&wS[srow*18 + (sseg+1)*4] = wreg1;
    __syncthreads();
    #pragma unroll
    for (int nt = 0; nt < 8; nt++) {
      bf16x8 bf = *(const bf16x8*)&wS[(nt*16 + m)*18 + quad*4];
      acc[nt] = __builtin_amdgcn_mfma_f32_16x16x32_bf16(af.v8, bf, acc[nt], 0, 0, 0);
    }
  }
  float* redS = wS;
  float* redQ = wS + 512;
  float* redM = wS + 1024;
  float* redN = wS + 1536;
  float mxr[8], mnr[8], ssr[8], sqr[8];
  #pragma unroll
  for (int nt = 0; nt < 8; nt++) {
    int col = nt*16 + m;
    float bp = biasp[colbase + col];
    float r0 = fmaxf(acc[nt].x + bp, 0.f);
    float r1 = fmaxf(acc[nt].y + bp, 0.f);
    float r2 = fmaxf(acc[nt].z + bp, 0.f);
    float r3 = fmaxf(acc[nt].w + bp, 0.f);
    float mx = fmaxf(fmaxf(r0, r1), fmaxf(r2, r3));
    float mn = fminf(fminf(r0, r1), fminf(r2, r3));
    float ss = r0 + r1 + r2 + r3;
    float s2 = r0*r0 + r1*r1 + r2*r2 + r3*r3;
    mx = fmaxf(mx, __shfl_xor(mx, 16, 64));
    mx = fmaxf(mx, __shfl_xor(mx, 32, 64));
    mn = fminf(mn, __shfl_xor(mn, 16, 64));
    mn = fminf(mn, __shfl_xor(mn, 32, 64));
    ss += __shfl_xor(ss, 16, 64);
    ss += __shfl_xor(ss, 32, 64);
    s2 += __shfl_xor(s2, 16, 64);
    s2 += __shfl_xor(s2, 32, 64);
    mxr[nt] = mx; mnr[nt] = mn; ssr[nt] = ss; sqr[nt] = s2;
  }
  __syncthreads();
  if (quad == 0) {
    #pragma unroll
    for (int nt = 0; nt < 8; nt++) {
      int col = nt*16 + m;
      redS[w*128 + col] = ssr[nt];
      redQ[w*128 + col] = sqr[nt];
      redM[w*128 + col] = mxr[nt];
      redN[w*128 + col] = mnr[nt];
    }
  }
  __syncthreads();
  if (tid < 128) {
    float ts  = redS[tid] + redS[128+tid] + redS[256+tid] + redS[384+tid];
    float tq  = redQ[tid] + redQ[128+tid] + redQ[256+tid] + redQ[384+tid];
    float mxc = fmaxf(fmaxf(redM[tid], redM[128+tid]), fmaxf(redM[256+tid], redM[384+tid]));
    float mnc = fminf(fminf(redN[tid], redN[128+tid]), fminf(redN[256+tid], redN[384+tid]));
    int row = blockIdx.x & (NSH - 1);
    atomicAdd(&stats[row*1024 + 512 + colbase + tid], ts);
    atomicAdd(&stats[row*1024 + 768 + colbase + tid], tq);
    int b  = blockIdx.x >> 8;
    int sh = blockIdx.x & (PSH - 1);
    atomicMax((int*)&pmaxs[((size_t)sh*BB + b)*DD + colbase + tid], __float_as_int(mxc));
    atomicMin((int*)&pmins[((size_t)sh*BB + b)*DD + colbase + tid], __float_as_int(mnc));
  }
}

// ---------------- final: one block per batch (R18-proven)
__global__ __launch_bounds__(256) void finalk(const float* __restrict__ pmaxs, const float* __restrict__ pmins,
    const float* __restrict__ stats, const float* __restrict__ g2, const float* __restrict__ be2,
    const float* __restrict__ W1, const float* __restrict__ b1,
    const float* __restrict__ W2, const float* __restrict__ b2,
    float* __restrict__ out)
{
  __shared__ float pl[256];
  __shared__ float hl[256];
  __shared__ float red[4];
  int c = threadIdx.x;
  int b = blockIdx.x;
  const float inv = 1.f / (float)NEDGE;
  float sm = 0.f, sq2 = 0.f;
  #pragma unroll 1
  for (int r = 0; r < NSH; r++) {
    sm  += stats[r*1024 + 512 + c];
    sq2 += stats[r*1024 + 768 + c];
  }
  float m = sm * inv;
  float var = sq2*inv - m*m;
  float s2 = g2[c] / sqrtf(var + BN_EPS);
  float t2 = be2[c] - m*s2;
  float mx = -3.4e38f, mn = 3.4e38f;
  #pragma unroll 1
  for (int s = 0; s < PSH; s++) {
    mx = fmaxf(mx, pmaxs[((size_t)s*BB + b)*DD + c]);
    mn = fminf(mn, pmins[((size_t)s*BB + b)*DD + c]);
  }
  pl[c] = (s2 >= 0.f) ? s2*mx + t2 : s2*mn + t2;
  __syncthreads();
  float h = b1[c];
  #pragma unroll 4
  for (int k = 0; k < 256; k++) h += pl[k]*W1[k*256 + c];
  hl[c] = fmaxf(h, 0.f);
  __syncthreads();
  float o = b2[c];
  #pragma unroll 4
  for (int k = 0; k < 256; k++) o += hl[k]*W2[k*256 + c];
  o = fmaxf(o, 0.f);
  float s = o*o;
  #pragma unroll
  for (int mm = 1; mm <= 32; mm <<= 1) s += __shfl_xor(s, mm, 64);
  if ((c & 63) == 0) red[c >> 6] = s;
  __syncthreads();
  float tot = red[0] + red[1] + red[2] + red[3];
  out[b*256 + c] = o / fmaxf(sqrtf(tot), 1e-12f);
}

extern "C" void kernel_launch(void* const* d_in, const int* in_sizes, int n_in,
                              void* d_out, int out_size, void* d_ws, size_t ws_size,
                              hipStream_t stream) {
  (void)in_sizes; (void)n_in; (void)out_size; (void)ws_size;
  const int*   cls       = (const int*)  d_in[0];
  const float* colors    = (const float*)d_in[1];
  const float* positions = (const float*)d_in[2];
  const float* ctab      = (const float*)d_in[3];
  const float* pW1 = (const float*)d_in[4];
  const float* pb1 = (const float*)d_in[5];
  const float* pW2 = (const float*)d_in[6];
  const float* pb2 = (const float*)d_in[7];
  const float* cW1 = (const float*)d_in[8];
  const float* cb1 = (const float*)d_in[9];
  const float* cW2 = (const float*)d_in[10];
  const float* cb2 = (const float*)d_in[11];
  const float* mW  = (const float*)d_in[12];
  const float* mb  = (const float*)d_in[13];
  const float* gW1 = (const float*)d_in[14];
  const float* gb1 = (const float*)d_in[15];
  const float* gg1 = (const float*)d_in[16];
  const float* gbe1= (const float*)d_in[17];
  const float* gW2 = (const float*)d_in[18];
  const float* gb2 = (const float*)d_in[19];
  const float* gg2 = (const float*)d_in[20];
  const float* gbe2= (const float*)d_in[21];
  const float* lW1 = (const float*)d_in[22];
  const float* lb1 = (const float*)d_in[23];
  const float* lW2 = (const float*)d_in[24];
  const float* lb2 = (const float*)d_in[25];
  float* out = (float*)d_out;

  float* wsf   = (float*)d_ws;
  unsigned short* feathi = (unsigned short*)(wsf + OFF_FEAT);
  unsigned short* featlo = feathi + (size_t)NPTS*768;
  float* sq    = wsf + OFF_SQ;
  int*   idxg  = (int*)(wsf + OFF_IDX);
  float* u     = wsf + OFF_U;
  float* v     = wsf + OFF_V;
  unsigned short* w2bf = (unsigned short*)(wsf + OFF_W2BF);
  float* biasp = wsf + OFF_BIASP;
  unsigned short* xhi = (unsigned short*)(wsf + OFF_XHI);
  unsigned short* xlo = (unsigned short*)(wsf + OFF_XLO);
  unsigned short* mwh = (unsigned short*)(wsf + OFF_MWH);
  unsigned short* mwl = (unsigned short*)(wsf + OFF_MWL);
  unsigned short* Wuh = (unsigned short*)(wsf + OFF_WUH);
  unsigned short* Wul = (unsigned short*)(wsf + OFF_WUL);
  unsigned short* Wbh = (unsigned short*)(wsf + OFF_WBH);
  unsigned short* Wbl = (unsigned short*)(wsf + OFF_WBL);
  float* stats = wsf + OFF_STATS;
  float* pmaxs = wsf + OFF_PMAXS;
  float* pmins = wsf + OFF_PMINS;
  // partial kNN buffers overlay feathi/featlo region (dead after gemm768)
  float* pdg   = wsf + OFF_FEAT;
  int*   pjg   = (int*)(wsf + OFF_FEAT + (size_t)NPTS*32);

  // stats + pmaxs + sq are contiguous -> one zero memset
  hipMemsetAsync(stats, 0, (NSH*1024 + PSH*BB*DD + NPTS)*sizeof(float), stream);
  hipMemsetAsync(pmins, 0x7f, PSH*BB*DD*sizeof(float), stream);   // ~3.39e38f

  prepk<<<4096 + 768 + 256, 256, 0, stream>>>(cls, colors, positions, ctab,
                                              pW1, pb1, pW2, pb2, cW1, cb1, cW2, cb2,
                                              feathi, featlo, mW, mwh, mwl,
                                              gW1, Wuh, Wul, Wbh, Wbl);
  gemm768<<<dim3(NPTS/64, 2), 256, 0, stream>>>(feathi, featlo, mwh, mwl, mb, sq, xhi, xlo);
  knnuv<<<2048, 256, 0, stream>>>(xhi, xlo, sq, pdg, pjg, Wuh, Wul, Wbh, Wbl, u, v);
  knnmerge<<<NPTS/256, 256, 0, stream>>>(pdg, pjg, idxg);
  bn1stats<<<NPTS/16, 256, 0, stream>>>(u, v, idxg, gb1, stats);
  prep2<<<1, 256, 0, stream>>>(stats, gg1, gbe1, gW2, gb2, w2bf, biasp);
  edgek<<<dim3(NEDGE/64, 2), 256, 0, stream>>>(u, v, idxg, gb1, w2bf, biasp, pmaxs, pmins, stats);
  finalk<<<BB, 256, 0, stream>>>(pmaxs, pmins, stats, gg2, gbe2, lW1, lb1, lW2, lb2, out);
}

// Round 27
// 518.729 us; speedup vs baseline: 1.1681x; 1.1681x over previous
//
#include <hip/hip_runtime.h>
#include <math.h>

#define BB 8
#define NN 2048
#define DD 256
#define KNN 8
#define NPTS (BB*NN)        // 16384
#define NEDGE (NPTS*KNN)    // 131072
#define BN_EPS 1e-5f
#define NSH 64              // shadow copies for BN stats accumulation
#define PSH 32              // shadow copies for pooled max/min

// ---- workspace layout (float offsets) ----
#define OFF_X      0
#define OFF_FEAT   (OFF_X + NPTS*DD)          // region holds feathi+featlo (ushort), pdg/pjg overlay
#define OFF_STATS  (OFF_FEAT + NPTS*3*DD)     // NSH x 1024
#define OFF_PMAXS  (OFF_STATS + NSH*1024)     // PSH x BB x 256
#define OFF_SQ     (OFF_PMAXS + PSH*BB*DD)    // NPTS
#define OFF_PMINS  (OFF_SQ + NPTS)            // PSH x BB x 256
#define OFF_IDX    (OFF_PMINS + PSH*BB*DD)
#define OFF_U      (OFF_IDX + NEDGE)
#define OFF_V      (OFF_U + NPTS*DD)
#define OFF_W2BF   (OFF_V + NPTS*DD)          // 256x256 ushort
#define OFF_BIASP  (OFF_W2BF + 32768)
#define OFF_XHI    (OFF_BIASP + DD)           // NPTS x 256 ushort
#define OFF_XLO    (OFF_XHI + NPTS*DD/2)      // NPTS x 256 ushort
#define OFF_MWH    (OFF_XLO + NPTS*DD/2)      // 256x768 ushort (transposed)
#define OFF_MWL    (OFF_MWH + 98304)
#define OFF_WUH    (OFF_MWL + 98304)          // 4 uv weight tables, 256x256 ushort each
#define OFF_WUL    (OFF_WUH + 32768)
#define OFF_WBH    (OFF_WUL + 32768)
#define OFF_WBL    (OFF_WBH + 32768)

typedef __attribute__((ext_vector_type(8))) short bf16x8;
typedef __attribute__((ext_vector_type(4))) float f32x4;

__device__ __forceinline__ unsigned short f2bf(float f) {
  unsigned int u = __float_as_uint(f);
  u += 0x7FFF + ((u >> 16) & 1);   // round to nearest even
  return (unsigned short)(u >> 16);
}
__device__ __forceinline__ float bf2f(unsigned short h) {
  return __uint_as_float((unsigned int)h << 16);
}

// ---------------- merged prep: featurize (bx<4096) | prep_mw (bx<4864) | prep_uvw.
// Tiny uniform branches -> no VGPR penalty (kept from R26; the knnuv merge is reverted).
__global__ __launch_bounds__(256) void prepk(
    const int* __restrict__ cls, const float* __restrict__ colors, const float* __restrict__ positions,
    const float* __restrict__ ctab,
    const float* __restrict__ pW1, const float* __restrict__ pb1, const float* __restrict__ pW2, const float* __restrict__ pb2,
    const float* __restrict__ cW1, const float* __restrict__ cb1, const float* __restrict__ cW2, const float* __restrict__ cb2,
    unsigned short* __restrict__ feathi, unsigned short* __restrict__ featlo,
    const float* __restrict__ mW,
    unsigned short* __restrict__ mwh, unsigned short* __restrict__ mwl,
    const float* __restrict__ gW1,
    unsigned short* __restrict__ Wuh, unsigned short* __restrict__ Wul,
    unsigned short* __restrict__ Wbh, unsigned short* __restrict__ Wbl)
{
  __shared__ float wbuf[4][64];
  int bx = blockIdx.x;
  int tid = threadIdx.x;
  if (bx < 4096) {
    int wv = tid >> 6, lane = tid & 63;
    int p = bx*4 + wv;
    if (lane < 32) {
      float c0 = colors[p*3+0], c1 = colors[p*3+1], c2 = colors[p*3+2];
      wbuf[wv][lane] = fmaxf(c0*cW1[lane] + c1*cW1[32+lane] + c2*cW1[64+lane] + cb1[lane], 0.f);
    } else {
      int l = lane - 32;
      float q0 = positions[p*3+0], q1 = positions[p*3+1], q2 = positions[p*3+2];
      wbuf[wv][32+l] = fmaxf(q0*pW1[l] + q1*pW1[32+l] + q2*pW1[64+l] + pb1[l], 0.f);
    }
    __syncthreads();
    int c = lane*4;
    float4 ce4 = *(const float4*)&ctab[(size_t)cls[p]*DD + c];
    float4 col4 = *(const float4*)&cb2[c];
    float4 pos4 = *(const float4*)&pb2[c];
    #pragma unroll
    for (int k = 0; k < 32; k++) {
      float ch = wbuf[wv][k], ph = wbuf[wv][32+k];
      float4 cw = *(const float4*)&cW2[k*DD + c];
      float4 pw = *(const float4*)&pW2[k*DD + c];
      col4.x += ch*cw.x; col4.y += ch*cw.y; col4.z += ch*cw.z; col4.w += ch*cw.w;
      pos4.x += ph*pw.x; pos4.y += ph*pw.y; pos4.z += ph*pw.z; pos4.w += ph*pw.w;
    }
    col4.x = fmaxf(col4.x, 0.f); col4.y = fmaxf(col4.y, 0.f);
    col4.z = fmaxf(col4.z, 0.f); col4.w = fmaxf(col4.w, 0.f);
    pos4.x = fmaxf(pos4.x, 0.f); pos4.y = fmaxf(pos4.y, 0.f);
    pos4.z = fmaxf(pos4.z, 0.f); pos4.w = fmaxf(pos4.w, 0.f);
    float sce  = ce4.x*ce4.x + ce4.y*ce4.y + ce4.z*ce4.z + ce4.w*ce4.w;
    float scol = col4.x*col4.x + col4.y*col4.y + col4.z*col4.z + col4.w*col4.w;
    float spos = pos4.x*pos4.x + pos4.y*pos4.y + pos4.z*pos4.z + pos4.w*pos4.w;
    #pragma unroll
    for (int m = 1; m <= 32; m <<= 1) {
      sce  += __shfl_xor(sce,  m, 64);
      scol += __shfl_xor(scol, m, 64);
      spos += __shfl_xor(spos, m, 64);
    }
    float ice = 1.f / fmaxf(sqrtf(sce),  1e-12f);
    float icl = 1.f / fmaxf(sqrtf(scol), 1e-12f);
    float ips = 1.f / fmaxf(sqrtf(spos), 1e-12f);
    float o[3][4] = {
      {ce4.x*ice,  ce4.y*ice,  ce4.z*ice,  ce4.w*ice},
      {col4.x*icl, col4.y*icl, col4.z*icl, col4.w*icl},
      {pos4.x*ips, pos4.y*ips, pos4.z*ips, pos4.w*ips}
    };
    #pragma unroll
    for (int sgm = 0; sgm < 3; sgm++) {
      unsigned short h[4], l[4];
      #pragma unroll
      for (int cc = 0; cc < 4; cc++) {
        h[cc] = f2bf(o[sgm][cc]);
        l[cc] = f2bf(o[sgm][cc] - bf2f(h[cc]));
      }
      size_t off = (size_t)p*768 + sgm*256 + c;
      *(uint2*)&feathi[off] = make_uint2((unsigned)h[0] | ((unsigned)h[1] << 16),
                                         (unsigned)h[2] | ((unsigned)h[3] << 16));
      *(uint2*)&featlo[off] = make_uint2((unsigned)l[0] | ((unsigned)l[1] << 16),
                                         (unsigned)l[2] | ((unsigned)l[3] << 16));
    }
  } else if (bx < 4096 + 768) {
    int k = bx - 4096;
    int n = tid;
    float wgt = mW[(size_t)k*DD + n];
    unsigned short h = f2bf(wgt);
    mwh[(size_t)n*768 + k] = h;
    mwl[(size_t)n*768 + k] = f2bf(wgt - bf2f(h));
  } else {
    int k = bx - (4096 + 768);
    int n = tid;
    float t = gW1[(size_t)k*DD + n];
    float b = gW1[(size_t)(k + DD)*DD + n];
    float wu = t - b;
    unsigned short uh = f2bf(wu), bh = f2bf(b);
    Wuh[(size_t)n*DD + k] = uh;
    Wul[(size_t)n*DD + k] = f2bf(wu - bf2f(uh));
    Wbh[(size_t)n*DD + k] = bh;
    Wbl[(size_t)n*DD + k] = f2bf(b - bf2f(bh));
  }
}

// ---------------- merge GEMM via split-bf16 MFMA, col-split x2 (R24-proven; no x write)
__global__ __launch_bounds__(256) void gemm768(
    const unsigned short* __restrict__ feathi, const unsigned short* __restrict__ featlo,
    const unsigned short* __restrict__ mwh, const unsigned short* __restrict__ mwl,
    const float* __restrict__ mb,
    float* __restrict__ sqo,
    unsigned short* __restrict__ xhi, unsigned short* __restrict__ xlo)
{
  __shared__ float wSh[128*18];
  __shared__ float wSl[128*18];
  int tid = threadIdx.x;
  int w = tid >> 6, lane = tid & 63;
  int m = lane & 15, quad = lane >> 4;
  int rowbase = blockIdx.x * 64;
  int colbase = blockIdx.y * 128;
  size_t aoff = (size_t)(rowbase + w*16 + m)*768;
  int srow = tid >> 1;
  int sseg = (tid & 1) * 2;
  f32x4 acc[8];
  #pragma unroll
  for (int t = 0; t < 8; t++) acc[t] = (f32x4){0.f, 0.f, 0.f, 0.f};
  #pragma unroll 1
  for (int c = 0; c < 24; c++) {
    int k0 = c*32 + quad*8;
    bf16x8 ah = *(const bf16x8*)(feathi + aoff + k0);
    bf16x8 al = *(const bf16x8*)(featlo + aoff + k0);
    const float* wrh = (const float*)(mwh + (size_t)(colbase + srow)*768 + c*32);
    const float* wrl = (const float*)(mwl + (size_t)(colbase + srow)*768 + c*32);
    float4 wh0 = *(const float4*)(wrh + sseg*4);
    float4 wh1 = *(const float4*)(wrh + (sseg+1)*4);
    float4 wl0 = *(const float4*)(wrl + sseg*4);
    float4 wl1 = *(const float4*)(wrl + (sseg+1)*4);
    __syncthreads();
    *(float4*)&wSh[srow*18 + sseg*4]     = wh0;
    *(float4*)&wSh[srow*18 + (sseg+1)*4] = wh1;
    *(float4*)&wSl[srow*18 + sseg*4]     = wl0;
    *(float4*)&wSl[srow*18 + (sseg+1)*4] = wl1;
    __syncthreads();
    #pragma unroll
    for (int nt = 0; nt < 8; nt++) {
      bf16x8 bh = *(const bf16x8*)&wSh[(nt*16 + m)*18 + quad*4];
      bf16x8 bl = *(const bf16x8*)&wSl[(nt*16 + m)*18 + quad*4];
      acc[nt] = __builtin_amdgcn_mfma_f32_16x16x32_bf16(ah, bh, acc[nt], 0, 0, 0);
      acc[nt] = __builtin_amdgcn_mfma_f32_16x16x32_bf16(ah, bl, acc[nt], 0, 0, 0);
      acc[nt] = __builtin_amdgcn_mfma_f32_16x16x32_bf16(al, bh, acc[nt], 0, 0, 0);
    }
  }
  float sqp[4] = {0.f, 0.f, 0.f, 0.f};
  #pragma unroll
  for (int nt = 0; nt < 8; nt++) {
    int col = colbase + nt*16 + m;
    float bp = mb[col];
    #pragma unroll
    for (int r = 0; r < 4; r++) {
      float o = fmaxf(acc[nt][r] + bp, 0.f);
      int row = rowbase + w*16 + quad*4 + r;
      unsigned short h = f2bf(o);
      xhi[(size_t)row*DD + col] = h;
      xlo[(size_t)row*DD + col] = f2bf(o - bf2f(h));
      sqp[r] += o*o;
    }
  }
  #pragma unroll
  for (int r = 0; r < 4; r++) {
    #pragma unroll
    for (int mm = 1; mm <= 8; mm <<= 1) sqp[r] += __shfl_xor(sqp[r], mm, 64);
  }
  if (m == 0) {
    #pragma unroll
    for (int r = 0; r < 4; r++)
      atomicAdd(&sqo[rowbase + w*16 + quad*4 + r], sqp[r]);
  }
}

// ---------------- u/v GEMM via split-bf16 MFMA, col-split + uv-split (R25-proven)
__global__ __launch_bounds__(256) void gemmuv(
    const unsigned short* __restrict__ xhi, const unsigned short* __restrict__ xlo,
    const unsigned short* __restrict__ Wuh, const unsigned short* __restrict__ Wul,
    const unsigned short* __restrict__ Wbh, const unsigned short* __restrict__ Wbl,
    float* __restrict__ U, float* __restrict__ V)
{
  __shared__ float wSh[128*18];
  __shared__ float wSl[128*18];
  int tid = threadIdx.x;
  int w = tid >> 6, lane = tid & 63;
  int m = lane & 15, quad = lane >> 4;
  int rowbase = blockIdx.x * 64;
  int uv = blockIdx.y >> 1;
  int colbase = (blockIdx.y & 1) * 128;
  const unsigned short* Wh = uv ? Wbh : Wuh;
  const unsigned short* Wl = uv ? Wbl : Wul;
  float* Out = uv ? V : U;
  size_t aoff = (size_t)(rowbase + w*16 + m)*DD;
  int srow = tid >> 1;
  int sseg = (tid & 1) * 2;
  f32x4 acc[8];
  #pragma unroll
  for (int t = 0; t < 8; t++) acc[t] = (f32x4){0.f, 0.f, 0.f, 0.f};
  #pragma unroll 1
  for (int c = 0; c < 8; c++) {
    int k0 = c*32 + quad*8;
    bf16x8 ah = *(const bf16x8*)(xhi + aoff + k0);
    bf16x8 al = *(const bf16x8*)(xlo + aoff + k0);
    const float* wrh = (const float*)(Wh + (size_t)(colbase + srow)*DD + c*32);
    const float* wrl = (const float*)(Wl + (size_t)(colbase + srow)*DD + c*32);
    float4 wh0 = *(const float4*)(wrh + sseg*4);
    float4 wh1 = *(const float4*)(wrh + (sseg+1)*4);
    float4 wl0 = *(const float4*)(wrl + sseg*4);
    float4 wl1 = *(const float4*)(wrl + (sseg+1)*4);
    __syncthreads();
    *(float4*)&wSh[srow*18 + sseg*4]     = wh0;
    *(float4*)&wSh[srow*18 + (sseg+1)*4] = wh1;
    *(float4*)&wSl[srow*18 + sseg*4]     = wl0;
    *(float4*)&wSl[srow*18 + (sseg+1)*4] = wl1;
    __syncthreads();
    #pragma unroll
    for (int nt = 0; nt < 8; nt++) {
      bf16x8 bh = *(const bf16x8*)&wSh[(nt*16 + m)*18 + quad*4];
      bf16x8 bl = *(const bf16x8*)&wSl[(nt*16 + m)*18 + quad*4];
      acc[nt] = __builtin_amdgcn_mfma_f32_16x16x32_bf16(ah, bh, acc[nt], 0, 0, 0);
      acc[nt] = __builtin_amdgcn_mfma_f32_16x16x32_bf16(ah, bl, acc[nt], 0, 0, 0);
      acc[nt] = __builtin_amdgcn_mfma_f32_16x16x32_bf16(al, bh, acc[nt], 0, 0, 0);
    }
  }
  #pragma unroll
  for (int nt = 0; nt < 8; nt++) {
    int col = colbase + nt*16 + m;
    #pragma unroll
    for (int r = 0; r < 4; r++) {
      int row = rowbase + w*16 + quad*4 + r;
      Out[(size_t)row*DD + col] = acc[nt][r];
    }
  }
}

// ---------------- kNN via split-bf16 MFMA, LDS-staged j-rows, register-hoisted A
// (R20/R23-proven).
__global__ __launch_bounds__(256) void knnk(
    const unsigned short* __restrict__ xhi, const unsigned short* __restrict__ xlo,
    const float* __restrict__ sq,
    float* __restrict__ pdg, int* __restrict__ pjg)
{
  __shared__ float smem[4736];
  float* jh = smem;                 // 64 rows x 36 floats
  float* jl = smem + 2304;
  float (*dt)[65] = (float(*)[65])smem;
  float* sqI = smem + 4608;
  float* sqJ = smem + 4672;
  int tid = threadIdx.x;
  int q  = blockIdx.x & 3;
  int it = (blockIdx.x >> 2) & 31;
  int bb = blockIdx.x >> 7;
  int ibase = it * 64;
  const unsigned short* xhb = xhi + (size_t)bb*NN*DD;
  const unsigned short* xlb = xlo + (size_t)bb*NN*DD;
  const float* sqb = sq + (size_t)bb*NN;
  int w = tid >> 6, lane = tid & 63;
  int m = lane & 15, quad = lane >> 4;
  int selrow = tid & 63, selseg = tid >> 6;
  size_t aoff = (size_t)(ibase + w*16 + m)*DD;
  int srow = tid >> 2;
  int sseg = tid & 3;
  bf16x8 ahr[8], alr[8];
  #pragma unroll
  for (int c = 0; c < 8; c++) {
    int k0 = c*32 + quad*8;
    ahr[c] = *(const bf16x8*)(xhb + aoff + k0);
    alr[c] = *(const bf16x8*)(xlb + aoff + k0);
  }
  float bd[8]; int bj[8];
  #pragma unroll
  for (int s = 0; s < 8; s++) { bd[s] = 3.4e38f; bj[s] = 0; }
  if (tid < 64) sqI[tid] = sqb[ibase + tid];
  #pragma unroll 1
  for (int jt = 0; jt < 8; jt++) {
    int jbase = q*512 + jt*64;
    if (tid < 64) sqJ[tid] = sqb[jbase + tid];
    f32x4 acc[4];
    #pragma unroll
    for (int t = 0; t < 4; t++) acc[t] = (f32x4){0.f, 0.f, 0.f, 0.f};
    #pragma unroll
    for (int c2 = 0; c2 < 4; c2++) {
      size_t gb = (size_t)(jbase + srow)*DD + c2*64;
      float4 h0 = *(const float4*)((const float*)(xhb + gb) + sseg*4);
      float4 h1 = *(const float4*)((const float*)(xhb + gb) + (sseg+4)*4);
      float4 l0 = *(const float4*)((const float*)(xlb + gb) + sseg*4);
      float4 l1 = *(const float4*)((const float*)(xlb + gb) + (sseg+4)*4);
      __syncthreads();
      *(float4*)&jh[srow*36 + sseg*4]     = h0;
      *(float4*)&jh[srow*36 + (sseg+4)*4] = h1;
      *(float4*)&jl[srow*36 + sseg*4]     = l0;
      *(float4*)&jl[srow*36 + (sseg+4)*4] = l1;
      __syncthreads();
      #pragma unroll
      for (int kk = 0; kk < 2; kk++) {
        bf16x8 ah = ahr[c2*2 + kk];
        bf16x8 al = alr[c2*2 + kk];
        int lofs = kk*16 + quad*4;
        #pragma unroll
        for (int nt = 0; nt < 4; nt++) {
          int r = nt*16 + m;
          bf16x8 bh = *(const bf16x8*)&jh[r*36 + lofs];
          bf16x8 bl = *(const bf16x8*)&jl[r*36 + lofs];
          acc[nt] = __builtin_amdgcn_mfma_f32_16x16x32_bf16(ah, bh, acc[nt], 0, 0, 0);
          acc[nt] = __builtin_amdgcn_mfma_f32_16x16x32_bf16(ah, bl, acc[nt], 0, 0, 0);
          acc[nt] = __builtin_amdgcn_mfma_f32_16x16x32_bf16(al, bh, acc[nt], 0, 0, 0);
        }
      }
    }
    __syncthreads();
    #pragma unroll
    for (int nt = 0; nt < 4; nt++) {
      int col = nt*16 + m;
      float sj = sqJ[col];
      #pragma unroll
      for (int r = 0; r < 4; r++) {
        int rowl = w*16 + quad*4 + r;
        dt[rowl][col] = sqI[rowl] + sj - 2.f*acc[nt][r];
      }
    }
    __syncthreads();
    int cb = selseg*16;
    #pragma unroll
    for (int s = 0; s < 16; s++) {
      float dv = dt[selrow][cb + s];
      if (dv < bd[7]) {
        bd[7] = dv; bj[7] = jbase + cb + s;
        #pragma unroll
        for (int t = 7; t >= 1; t--) {
          if (bd[t] < bd[t-1]) {
            float td = bd[t]; bd[t] = bd[t-1]; bd[t-1] = td;
            int   tj = bj[t]; bj[t] = bj[t-1]; bj[t-1] = tj;
          }
        }
      }
    }
  }
  __syncthreads();
  float* pdl = &smem[0];
  int*   pjl = (int*)&smem[2048];
  #pragma unroll
  for (int s = 0; s < 8; s++) {
    pdl[tid*8 + s] = bd[s];
    pjl[tid*8 + s] = bj[s];
  }
  __syncthreads();
  if (tid < 64) {
    float md[8]; int mj[8];
    #pragma unroll
    for (int s = 0; s < 8; s++) { md[s] = 3.4e38f; mj[s] = 0; }
    #pragma unroll 1
    for (int g = 0; g < 4; g++) {
      int base = (g*64 + tid)*8;
      #pragma unroll
      for (int s = 0; s < 8; s++) {
        float dv = pdl[base + s];
        if (dv < md[7]) {
          md[7] = dv; mj[7] = pjl[base + s];
          #pragma unroll
          for (int t = 7; t >= 1; t--) {
            if (md[t] < md[t-1]) {
              float td = md[t]; md[t] = md[t-1]; md[t-1] = td;
              int   tj = mj[t]; mj[t] = mj[t-1]; mj[t-1] = tj;
            }
          }
        }
      }
    }
    size_t gbase = ((size_t)(bb*NN + ibase + tid))*32 + (size_t)q*8;
    #pragma unroll
    for (int s = 0; s < 8; s++) {
      pdg[gbase + s] = md[s];
      pjg[gbase + s] = bb*NN + mj[s];
    }
  }
}

// ---------------- merge 4 quarter-lists per point -> final 8 neighbor indices
__global__ __launch_bounds__(256) void knnmerge(const float* __restrict__ pdg, const int* __restrict__ pjg,
                                                int* __restrict__ idxg)
{
  int p = blockIdx.x*256 + threadIdx.x;
  float md[8]; int mj[8];
  #pragma unroll
  for (int s = 0; s < 8; s++) { md[s] = 3.4e38f; mj[s] = 0; }
  size_t base = (size_t)p*32;
  #pragma unroll 1
  for (int s = 0; s < 32; s++) {
    float dv = pdg[base + s];
    if (dv < md[7]) {
      md[7] = dv; mj[7] = pjg[base + s];
      #pragma unroll
      for (int t = 7; t >= 1; t--) {
        if (md[t] < md[t-1]) {
          float td = md[t]; md[t] = md[t-1]; md[t-1] = td;
          int   tj = mj[t]; mj[t] = mj[t-1]; mj[t-1] = tj;
        }
      }
    }
  }
  #pragma unroll
  for (int s = 0; s < 8; s++) idxg[(size_t)p*8 + s] = mj[s];
}

// ---------------- BN1 stats: h1 = relu(u_i + v_j + b1), shadow-accumulator atomics
__global__ __launch_bounds__(256) void bn1stats(const float* __restrict__ u, const float* __restrict__ v,
    const int* __restrict__ idxg, const float* __restrict__ b1, float* __restrict__ stats)
{
  __shared__ int jL[128];
  int c = threadIdx.x;
  int n0 = blockIdx.x * 16;
  if (c < 128) jL[c] = idxg[(size_t)n0*8 + c];
  __syncthreads();
  float b1c = b1[c];
  float s = 0.f, s2 = 0.f;
  #pragma unroll 1
  for (int n = 0; n < 16; n++) {
    float uc = u[(size_t)(n0 + n)*DD + c];
    #pragma unroll
    for (int e = 0; e < 8; e++) {
      int j = jL[n*8 + e];
      float h = fmaxf(uc + v[(size_t)j*DD + c] + b1c, 0.f);
      s += h; s2 += h*h;
    }
  }
  int row = blockIdx.x & (NSH - 1);
  atomicAdd(&stats[row*1024 + c], s);
  atomicAdd(&stats[row*1024 + 256 + c], s2);
}

// ---------------- fold BN1 into layer-2 weights; emit TRANSPOSED bf16 weights
__global__ __launch_bounds__(256) void prep2(const float* __restrict__ stats, const float* __restrict__ g1,
    const float* __restrict__ be1, const float* __restrict__ gW2, const float* __restrict__ gb2,
    unsigned short* __restrict__ w2bf, float* __restrict__ biasp)
{
  __shared__ float s1L[256], t1L[256];
  int tid = threadIdx.x;
  const float inv = 1.f / (float)NEDGE;
  float sm = 0.f, sq2 = 0.f;
  #pragma unroll 1
  for (int r = 0; r < NSH; r++) {
    sm  += stats[r*1024 + tid];
    sq2 += stats[r*1024 + 256 + tid];
  }
  float m = sm * inv;
  float var = sq2*inv - m*m;
  float s1 = g1[tid] / sqrtf(var + BN_EPS);
  s1L[tid] = s1; t1L[tid] = be1[tid] - m*s1;
  __syncthreads();
  float bacc = gb2[tid];
  for (int k = 0; k < DD; k++) {
    float w = gW2[k*DD + tid];
    w2bf[(size_t)tid*DD + k] = f2bf(s1L[k]*w);
    bacc += t1L[k]*w;
  }
  biasp[tid] = bacc;
}

// ---------------- edge GEMM via bf16 MFMA, column-split x2 (R23-proven)
__global__ __launch_bounds__(256) void edgek(
    const float* __restrict__ u, const float* __restrict__ v, const int* __restrict__ idxg,
    const float* __restrict__ b1, const unsigned short* __restrict__ w2bf,
    const float* __restrict__ biasp,
    float* __restrict__ pmaxs, float* __restrict__ pmins, float* __restrict__ stats)
{
  __shared__ float wS[128*18];     // 9 KB
  int tid = threadIdx.x;
  int w = tid >> 6, lane = tid & 63;
  int m = lane & 15, quad = lane >> 4;
  int rowbase = blockIdx.x * 64;
  int colbase = blockIdx.y * 128;
  int edge = rowbase + w*16 + m;
  int iu = edge >> 3;
  int jv = idxg[edge];
  const float* urow = u + (size_t)iu*DD;
  const float* vrow = v + (size_t)jv*DD;
  int srow = tid >> 1;
  int sseg = (tid & 1) * 2;
  f32x4 acc[8];
  #pragma unroll
  for (int t = 0; t < 8; t++) acc[t] = (f32x4){0.f, 0.f, 0.f, 0.f};
  #pragma unroll 1
  for (int c = 0; c < 8; c++) {
    int k0 = c*32 + quad*8;
    float4 ua = *(const float4*)(urow + k0);
    float4 ub = *(const float4*)(urow + k0 + 4);
    float4 va = *(const float4*)(vrow + k0);
    float4 vb = *(const float4*)(vrow + k0 + 4);
    float4 ba = *(const float4*)(b1 + k0);
    float4 bb = *(const float4*)(b1 + k0 + 4);
    const float* wrow = (const float*)(w2bf + (size_t)(colbase + srow)*DD + c*32);
    float4 wreg0 = *(const float4*)(wrow + sseg*4);
    float4 wreg1 = *(const float4*)(wrow + (sseg+1)*4);
    float h0 = fmaxf(ua.x+va.x+ba.x, 0.f);
    float h1 = fmaxf(ua.y+va.y+ba.y, 0.f);
    float h2 = fmaxf(ua.z+va.z+ba.z, 0.f);
    float h3 = fmaxf(ua.w+va.w+ba.w, 0.f);
    float h4 = fmaxf(ub.x+vb.x+bb.x, 0.f);
    float h5 = fmaxf(ub.y+vb.y+bb.y, 0.f);
    float h6 = fmaxf(ub.z+vb.z+bb.z, 0.f);
    float h7 = fmaxf(ub.w+vb.w+bb.w, 0.f);
    union { bf16x8 v8; unsigned short s[8]; } af;
    af.s[0] = f2bf(h0); af.s[1] = f2bf(h1); af.s[2] = f2bf(h2); af.s[3] = f2bf(h3);
    af.s[4] = f2bf(h4); af.s[5] = f2bf(h5); af.s[6] = f2bf(h6); af.s[7] = f2bf(h7);
    __syncthreads();
    *(float4*)&wS[srow*18 + sseg*4]     = wreg0;
    *(float4*)&wS[srow*18 + (sseg+1)*4] = wreg1;
    __syncthreads();
    #pragma unroll
    for (int nt = 0; nt < 8; nt++) {
      bf16x8 bf = *(const bf16x8*)&wS[(nt*16 + m)*18 + quad*4];
      acc[nt] = __builtin_amdgcn_mfma_f32_16x16x32_bf16(af.v8, bf, acc[nt], 0, 0, 0);
    }
  }
  float* redS = wS;
  float* redQ = wS + 512;
  float* redM = wS + 1024;
  float* redN = wS + 1536;
  float mxr[8], mnr[8], ssr[8], sqr[8];
  #pragma unroll
  for (int nt = 0; nt < 8; nt++) {
    int col = nt*16 + m;
    float bp = biasp[colbase + col];
    float r0 = fmaxf(acc[nt].x + bp, 0.f);
    float r1 = fmaxf(acc[nt].y + bp, 0.f);
    float r2 = fmaxf(acc[nt].z + bp, 0.f);
    float r3 = fmaxf(acc[nt].w + bp, 0.f);
    float mx = fmaxf(fmaxf(r0, r1), fmaxf(r2, r3));
    float mn = fminf(fminf(r0, r1), fminf(r2, r3));
    float ss = r0 + r1 + r2 + r3;
    float s2 = r0*r0 + r1*r1 + r2*r2 + r3*r3;
    mx = fmaxf(mx, __shfl_xor(mx, 16, 64));
    mx = fmaxf(mx, __shfl_xor(mx, 32, 64));
    mn = fminf(mn, __shfl_xor(mn, 16, 64));
    mn = fminf(mn, __shfl_xor(mn, 32, 64));
    ss += __shfl_xor(ss, 16, 64);
    ss += __shfl_xor(ss, 32, 64);
    s2 += __shfl_xor(s2, 16, 64);
    s2 += __shfl_xor(s2, 32, 64);
    mxr[nt] = mx; mnr[nt] = mn; ssr[nt] = ss; sqr[nt] = s2;
  }
  __syncthreads();
  if (quad == 0) {
    #pragma unroll
    for (int nt = 0; nt < 8; nt++) {
      int col = nt*16 + m;
      redS[w*128 + col] = ssr[nt];
      redQ[w*128 + col] = sqr[nt];
      redM[w*128 + col] = mxr[nt];
      redN[w*128 + col] = mnr[nt];
    }
  }
  __syncthreads();
  if (tid < 128) {
    float ts  = redS[tid] + redS[128+tid] + redS[256+tid] + redS[384+tid];
    float tq  = redQ[tid] + redQ[128+tid] + redQ[256+tid] + redQ[384+tid];
    float mxc = fmaxf(fmaxf(redM[tid], redM[128+tid]), fmaxf(redM[256+tid], redM[384+tid]));
    float mnc = fminf(fminf(redN[tid], redN[128+tid]), fminf(redN[256+tid], redN[384+tid]));
    int row = blockIdx.x & (NSH - 1);
    atomicAdd(&stats[row*1024 + 512 + colbase + tid], ts);
    atomicAdd(&stats[row*1024 + 768 + colbase + tid], tq);
    int b  = blockIdx.x >> 8;
    int sh = blockIdx.x & (PSH - 1);
    atomicMax((int*)&pmaxs[((size_t)sh*BB + b)*DD + colbase + tid], __float_as_int(mxc));
    atomicMin((int*)&pmins[((size_t)sh*BB + b)*DD + colbase + tid], __float_as_int(mnc));
  }
}

// ---------------- final: one block per batch (R18-proven)
__global__ __launch_bounds__(256) void finalk(const float* __restrict__ pmaxs, const float* __restrict__ pmins,
    const float* __restrict__ stats, const float* __restrict__ g2, const float* __restrict__ be2,
    const float* __restrict__ W1, const float* __restrict__ b1,
    const float* __restrict__ W2, const float* __restrict__ b2,
    float* __restrict__ out)
{
  __shared__ float pl[256];
  __shared__ float hl[256];
  __shared__ float red[4];
  int c = threadIdx.x;
  int b = blockIdx.x;
  const float inv = 1.f / (float)NEDGE;
  float sm = 0.f, sq2 = 0.f;
  #pragma unroll 1
  for (int r = 0; r < NSH; r++) {
    sm  += stats[r*1024 + 512 + c];
    sq2 += stats[r*1024 + 768 + c];
  }
  float m = sm * inv;
  float var = sq2*inv - m*m;
  float s2 = g2[c] / sqrtf(var + BN_EPS);
  float t2 = be2[c] - m*s2;
  float mx = -3.4e38f, mn = 3.4e38f;
  #pragma unroll 1
  for (int s = 0; s < PSH; s++) {
    mx = fmaxf(mx, pmaxs[((size_t)s*BB + b)*DD + c]);
    mn = fminf(mn, pmins[((size_t)s*BB + b)*DD + c]);
  }
  pl[c] = (s2 >= 0.f) ? s2*mx + t2 : s2*mn + t2;
  __syncthreads();
  float h = b1[c];
  #pragma unroll 4
  for (int k = 0; k < 256; k++) h += pl[k]*W1[k*256 + c];
  hl[c] = fmaxf(h, 0.f);
  __syncthreads();
  float o = b2[c];
  #pragma unroll 4
  for (int k = 0; k < 256; k++) o += hl[k]*W2[k*256 + c];
  o = fmaxf(o, 0.f);
  float s = o*o;
  #pragma unroll
  for (int mm = 1; mm <= 32; mm <<= 1) s += __shfl_xor(s, mm, 64);
  if ((c & 63) == 0) red[c >> 6] = s;
  __syncthreads();
  float tot = red[0] + red[1] + red[2] + red[3];
  out[b*256 + c] = o / fmaxf(sqrtf(tot), 1e-12f);
}

extern "C" void kernel_launch(void* const* d_in, const int* in_sizes, int n_in,
                              void* d_out, int out_size, void* d_ws, size_t ws_size,
                              hipStream_t stream) {
  (void)in_sizes; (void)n_in; (void)out_size; (void)ws_size;
  const int*   cls       = (const int*)  d_in[0];
  const float* colors    = (const float*)d_in[1];
  const float* positions = (const float*)d_in[2];
  const float* ctab      = (const float*)d_in[3];
  const float* pW1 = (const float*)d_in[4];
  const float* pb1 = (const float*)d_in[5];
  const float* pW2 = (const float*)d_in[6];
  const float* pb2 = (const float*)d_in[7];
  const float* cW1 = (const float*)d_in[8];
  const float* cb1 = (const float*)d_in[9];
  const float* cW2 = (const float*)d_in[10];
  const float* cb2 = (const float*)d_in[11];
  const float* mW  = (const float*)d_in[12];
  const float* mb  = (const float*)d_in[13];
  const float* gW1 = (const float*)d_in[14];
  const float* gb1 = (const float*)d_in[15];
  const float* gg1 = (const float*)d_in[16];
  const float* gbe1= (const float*)d_in[17];
  const float* gW2 = (const float*)d_in[18];
  const float* gb2 = (const float*)d_in[19];
  const float* gg2 = (const float*)d_in[20];
  const float* gbe2= (const float*)d_in[21];
  const float* lW1 = (const float*)d_in[22];
  const float* lb1 = (const float*)d_in[23];
  const float* lW2 = (const float*)d_in[24];
  const float* lb2 = (const float*)d_in[25];
  float* out = (float*)d_out;

  float* wsf   = (float*)d_ws;
  unsigned short* feathi = (unsigned short*)(wsf + OFF_FEAT);
  unsigned short* featlo = feathi + (size_t)NPTS*768;
  float* sq    = wsf + OFF_SQ;
  int*   idxg  = (int*)(wsf + OFF_IDX);
  float* u     = wsf + OFF_U;
  float* v     = wsf + OFF_V;
  unsigned short* w2bf = (unsigned short*)(wsf + OFF_W2BF);
  float* biasp = wsf + OFF_BIASP;
  unsigned short* xhi = (unsigned short*)(wsf + OFF_XHI);
  unsigned short* xlo = (unsigned short*)(wsf + OFF_XLO);
  unsigned short* mwh = (unsigned short*)(wsf + OFF_MWH);
  unsigned short* mwl = (unsigned short*)(wsf + OFF_MWL);
  unsigned short* Wuh = (unsigned short*)(wsf + OFF_WUH);
  unsigned short* Wul = (unsigned short*)(wsf + OFF_WUL);
  unsigned short* Wbh = (unsigned short*)(wsf + OFF_WBH);
  unsigned short* Wbl = (unsigned short*)(wsf + OFF_WBL);
  float* stats = wsf + OFF_STATS;
  float* pmaxs = wsf + OFF_PMAXS;
  float* pmins = wsf + OFF_PMINS;
  // partial kNN buffers overlay feathi/featlo region (dead after gemm768)
  float* pdg   = wsf + OFF_FEAT;
  int*   pjg   = (int*)(wsf + OFF_FEAT + (size_t)NPTS*32);

  // stats + pmaxs + sq are contiguous -> one zero memset
  hipMemsetAsync(stats, 0, (NSH*1024 + PSH*BB*DD + NPTS)*sizeof(float), stream);
  hipMemsetAsync(pmins, 0x7f, PSH*BB*DD*sizeof(float), stream);   // ~3.39e38f

  prepk<<<4096 + 768 + 256, 256, 0, stream>>>(cls, colors, positions, ctab,
                                              pW1, pb1, pW2, pb2, cW1, cb1, cW2, cb2,
                                              feathi, featlo, mW, mwh, mwl,
                                              gW1, Wuh, Wul, Wbh, Wbl);
  gemm768<<<dim3(NPTS/64, 2), 256, 0, stream>>>(feathi, featlo, mwh, mwl, mb, sq, xhi, xlo);
  knnk<<<BB*32*4, 256, 0, stream>>>(xhi, xlo, sq, pdg, pjg);
  knnmerge<<<NPTS/256, 256, 0, stream>>>(pdg, pjg, idxg);
  gemmuv<<<dim3(NPTS/64, 4), 256, 0, stream>>>(xhi, xlo, Wuh, Wul, Wbh, Wbl, u, v);
  bn1stats<<<NPTS/16, 256, 0, stream>>>(u, v, idxg, gb1, stats);
  prep2<<<1, 256, 0, stream>>>(stats, gg1, gbe1, gW2, gb2, w2bf, biasp);
  edgek<<<dim3(NEDGE/64, 2), 256, 0, stream>>>(u, v, idxg, gb1, w2bf, biasp, pmaxs, pmins, stats);
  finalk<<<BB, 256, 0, stream>>>(pmaxs, pmins, stats, gg2, gbe2, lW1, lb1, lW2, lb2, out);
}

// Round 28
// 509.070 us; speedup vs baseline: 1.1902x; 1.0190x over previous
//
#include <hip/hip_runtime.h>
#include <math.h>

#define BB 8
#define NN 2048
#define DD 256
#define KNN 8
#define NPTS (BB*NN)        // 16384
#define NEDGE (NPTS*KNN)    // 131072
#define BN_EPS 1e-5f
#define NSH 64              // shadow copies for BN stats accumulation
#define PSH 32              // shadow copies for pooled max/min

// ---- workspace layout (float offsets) ----
#define OFF_X      0
#define OFF_FEAT   (OFF_X + NPTS*DD)          // region holds feathi+featlo (ushort), pdg/pjg overlay
#define OFF_STATS  (OFF_FEAT + NPTS*3*DD)     // NSH x 1024
#define OFF_PMAXS  (OFF_STATS + NSH*1024)     // PSH x BB x 256
#define OFF_SQ     (OFF_PMAXS + PSH*BB*DD)    // NPTS
#define OFF_PMINS  (OFF_SQ + NPTS)            // PSH x BB x 256
#define OFF_IDX    (OFF_PMINS + PSH*BB*DD)
#define OFF_U      (OFF_IDX + NEDGE)
#define OFF_V      (OFF_U + NPTS*DD)
#define OFF_W2BF   (OFF_V + NPTS*DD)          // 256x256 ushort
#define OFF_BIASP  (OFF_W2BF + 32768)
#define OFF_XHI    (OFF_BIASP + DD)           // NPTS x 256 ushort
#define OFF_XLO    (OFF_XHI + NPTS*DD/2)      // NPTS x 256 ushort
#define OFF_MWH    (OFF_XLO + NPTS*DD/2)      // 256x768 ushort (transposed)
#define OFF_MWL    (OFF_MWH + 98304)
#define OFF_WUH    (OFF_MWL + 98304)          // 4 uv weight tables, 256x256 ushort each
#define OFF_WUL    (OFF_WUH + 32768)
#define OFF_WBH    (OFF_WUL + 32768)
#define OFF_WBL    (OFF_WBH + 32768)

typedef __attribute__((ext_vector_type(8))) short bf16x8;
typedef __attribute__((ext_vector_type(4))) float f32x4;

__device__ __forceinline__ unsigned short f2bf(float f) {
  unsigned int u = __float_as_uint(f);
  u += 0x7FFF + ((u >> 16) & 1);   // round to nearest even
  return (unsigned short)(u >> 16);
}
__device__ __forceinline__ float bf2f(unsigned short h) {
  return __uint_as_float((unsigned int)h << 16);
}

// ---------------- merged prep: featurize (bx<4096) | prep_mw (bx<4864) | prep_uvw.
__global__ __launch_bounds__(256) void prepk(
    const int* __restrict__ cls, const float* __restrict__ colors, const float* __restrict__ positions,
    const float* __restrict__ ctab,
    const float* __restrict__ pW1, const float* __restrict__ pb1, const float* __restrict__ pW2, const float* __restrict__ pb2,
    const float* __restrict__ cW1, const float* __restrict__ cb1, const float* __restrict__ cW2, const float* __restrict__ cb2,
    unsigned short* __restrict__ feathi, unsigned short* __restrict__ featlo,
    const float* __restrict__ mW,
    unsigned short* __restrict__ mwh, unsigned short* __restrict__ mwl,
    const float* __restrict__ gW1,
    unsigned short* __restrict__ Wuh, unsigned short* __restrict__ Wul,
    unsigned short* __restrict__ Wbh, unsigned short* __restrict__ Wbl)
{
  __shared__ float wbuf[4][64];
  int bx = blockIdx.x;
  int tid = threadIdx.x;
  if (bx < 4096) {
    int wv = tid >> 6, lane = tid & 63;
    int p = bx*4 + wv;
    if (lane < 32) {
      float c0 = colors[p*3+0], c1 = colors[p*3+1], c2 = colors[p*3+2];
      wbuf[wv][lane] = fmaxf(c0*cW1[lane] + c1*cW1[32+lane] + c2*cW1[64+lane] + cb1[lane], 0.f);
    } else {
      int l = lane - 32;
      float q0 = positions[p*3+0], q1 = positions[p*3+1], q2 = positions[p*3+2];
      wbuf[wv][32+l] = fmaxf(q0*pW1[l] + q1*pW1[32+l] + q2*pW1[64+l] + pb1[l], 0.f);
    }
    __syncthreads();
    int c = lane*4;
    float4 ce4 = *(const float4*)&ctab[(size_t)cls[p]*DD + c];
    float4 col4 = *(const float4*)&cb2[c];
    float4 pos4 = *(const float4*)&pb2[c];
    #pragma unroll
    for (int k = 0; k < 32; k++) {
      float ch = wbuf[wv][k], ph = wbuf[wv][32+k];
      float4 cw = *(const float4*)&cW2[k*DD + c];
      float4 pw = *(const float4*)&pW2[k*DD + c];
      col4.x += ch*cw.x; col4.y += ch*cw.y; col4.z += ch*cw.z; col4.w += ch*cw.w;
      pos4.x += ph*pw.x; pos4.y += ph*pw.y; pos4.z += ph*pw.z; pos4.w += ph*pw.w;
    }
    col4.x = fmaxf(col4.x, 0.f); col4.y = fmaxf(col4.y, 0.f);
    col4.z = fmaxf(col4.z, 0.f); col4.w = fmaxf(col4.w, 0.f);
    pos4.x = fmaxf(pos4.x, 0.f); pos4.y = fmaxf(pos4.y, 0.f);
    pos4.z = fmaxf(pos4.z, 0.f); pos4.w = fmaxf(pos4.w, 0.f);
    float sce  = ce4.x*ce4.x + ce4.y*ce4.y + ce4.z*ce4.z + ce4.w*ce4.w;
    float scol = col4.x*col4.x + col4.y*col4.y + col4.z*col4.z + col4.w*col4.w;
    float spos = pos4.x*pos4.x + pos4.y*pos4.y + pos4.z*pos4.z + pos4.w*pos4.w;
    #pragma unroll
    for (int m = 1; m <= 32; m <<= 1) {
      sce  += __shfl_xor(sce,  m, 64);
      scol += __shfl_xor(scol, m, 64);
      spos += __shfl_xor(spos, m, 64);
    }
    float ice = 1.f / fmaxf(sqrtf(sce),  1e-12f);
    float icl = 1.f / fmaxf(sqrtf(scol), 1e-12f);
    float ips = 1.f / fmaxf(sqrtf(spos), 1e-12f);
    float o[3][4] = {
      {ce4.x*ice,  ce4.y*ice,  ce4.z*ice,  ce4.w*ice},
      {col4.x*icl, col4.y*icl, col4.z*icl, col4.w*icl},
      {pos4.x*ips, pos4.y*ips, pos4.z*ips, pos4.w*ips}
    };
    #pragma unroll
    for (int sgm = 0; sgm < 3; sgm++) {
      unsigned short h[4], l[4];
      #pragma unroll
      for (int cc = 0; cc < 4; cc++) {
        h[cc] = f2bf(o[sgm][cc]);
        l[cc] = f2bf(o[sgm][cc] - bf2f(h[cc]));
      }
      size_t off = (size_t)p*768 + sgm*256 + c;
      *(uint2*)&feathi[off] = make_uint2((unsigned)h[0] | ((unsigned)h[1] << 16),
                                         (unsigned)h[2] | ((unsigned)h[3] << 16));
      *(uint2*)&featlo[off] = make_uint2((unsigned)l[0] | ((unsigned)l[1] << 16),
                                         (unsigned)l[2] | ((unsigned)l[3] << 16));
    }
  } else if (bx < 4096 + 768) {
    int k = bx - 4096;
    int n = tid;
    float wgt = mW[(size_t)k*DD + n];
    unsigned short h = f2bf(wgt);
    mwh[(size_t)n*768 + k] = h;
    mwl[(size_t)n*768 + k] = f2bf(wgt - bf2f(h));
  } else {
    int k = bx - (4096 + 768);
    int n = tid;
    float t = gW1[(size_t)k*DD + n];
    float b = gW1[(size_t)(k + DD)*DD + n];
    float wu = t - b;
    unsigned short uh = f2bf(wu), bh = f2bf(b);
    Wuh[(size_t)n*DD + k] = uh;
    Wul[(size_t)n*DD + k] = f2bf(wu - bf2f(uh));
    Wbh[(size_t)n*DD + k] = bh;
    Wbl[(size_t)n*DD + k] = f2bf(b - bf2f(bh));
  }
}

// ---------------- merge GEMM via split-bf16 MFMA, col-split x2 (R24-proven; no x write)
__global__ __launch_bounds__(256) void gemm768(
    const unsigned short* __restrict__ feathi, const unsigned short* __restrict__ featlo,
    const unsigned short* __restrict__ mwh, const unsigned short* __restrict__ mwl,
    const float* __restrict__ mb,
    float* __restrict__ sqo,
    unsigned short* __restrict__ xhi, unsigned short* __restrict__ xlo)
{
  __shared__ float wSh[128*18];
  __shared__ float wSl[128*18];
  int tid = threadIdx.x;
  int w = tid >> 6, lane = tid & 63;
  int m = lane & 15, quad = lane >> 4;
  int rowbase = blockIdx.x * 64;
  int colbase = blockIdx.y * 128;
  size_t aoff = (size_t)(rowbase + w*16 + m)*768;
  int srow = tid >> 1;
  int sseg = (tid & 1) * 2;
  f32x4 acc[8];
  #pragma unroll
  for (int t = 0; t < 8; t++) acc[t] = (f32x4){0.f, 0.f, 0.f, 0.f};
  #pragma unroll 1
  for (int c = 0; c < 24; c++) {
    int k0 = c*32 + quad*8;
    bf16x8 ah = *(const bf16x8*)(feathi + aoff + k0);
    bf16x8 al = *(const bf16x8*)(featlo + aoff + k0);
    const float* wrh = (const float*)(mwh + (size_t)(colbase + srow)*768 + c*32);
    const float* wrl = (const float*)(mwl + (size_t)(colbase + srow)*768 + c*32);
    float4 wh0 = *(const float4*)(wrh + sseg*4);
    float4 wh1 = *(const float4*)(wrh + (sseg+1)*4);
    float4 wl0 = *(const float4*)(wrl + sseg*4);
    float4 wl1 = *(const float4*)(wrl + (sseg+1)*4);
    __syncthreads();
    *(float4*)&wSh[srow*18 + sseg*4]     = wh0;
    *(float4*)&wSh[srow*18 + (sseg+1)*4] = wh1;
    *(float4*)&wSl[srow*18 + sseg*4]     = wl0;
    *(float4*)&wSl[srow*18 + (sseg+1)*4] = wl1;
    __syncthreads();
    #pragma unroll
    for (int nt = 0; nt < 8; nt++) {
      bf16x8 bh = *(const bf16x8*)&wSh[(nt*16 + m)*18 + quad*4];
      bf16x8 bl = *(const bf16x8*)&wSl[(nt*16 + m)*18 + quad*4];
      acc[nt] = __builtin_amdgcn_mfma_f32_16x16x32_bf16(ah, bh, acc[nt], 0, 0, 0);
      acc[nt] = __builtin_amdgcn_mfma_f32_16x16x32_bf16(ah, bl, acc[nt], 0, 0, 0);
      acc[nt] = __builtin_amdgcn_mfma_f32_16x16x32_bf16(al, bh, acc[nt], 0, 0, 0);
    }
  }
  float sqp[4] = {0.f, 0.f, 0.f, 0.f};
  #pragma unroll
  for (int nt = 0; nt < 8; nt++) {
    int col = colbase + nt*16 + m;
    float bp = mb[col];
    #pragma unroll
    for (int r = 0; r < 4; r++) {
      float o = fmaxf(acc[nt][r] + bp, 0.f);
      int row = rowbase + w*16 + quad*4 + r;
      unsigned short h = f2bf(o);
      xhi[(size_t)row*DD + col] = h;
      xlo[(size_t)row*DD + col] = f2bf(o - bf2f(h));
      sqp[r] += o*o;
    }
  }
  #pragma unroll
  for (int r = 0; r < 4; r++) {
    #pragma unroll
    for (int mm = 1; mm <= 8; mm <<= 1) sqp[r] += __shfl_xor(sqp[r], mm, 64);
  }
  if (m == 0) {
    #pragma unroll
    for (int r = 0; r < 4; r++)
      atomicAdd(&sqo[rowbase + w*16 + quad*4 + r], sqp[r]);
  }
}

// ---------------- u/v GEMM via split-bf16 MFMA, col-split + uv-split (R25-proven)
__global__ __launch_bounds__(256) void gemmuv(
    const unsigned short* __restrict__ xhi, const unsigned short* __restrict__ xlo,
    const unsigned short* __restrict__ Wuh, const unsigned short* __restrict__ Wul,
    const unsigned short* __restrict__ Wbh, const unsigned short* __restrict__ Wbl,
    float* __restrict__ U, float* __restrict__ V)
{
  __shared__ float wSh[128*18];
  __shared__ float wSl[128*18];
  int tid = threadIdx.x;
  int w = tid >> 6, lane = tid & 63;
  int m = lane & 15, quad = lane >> 4;
  int rowbase = blockIdx.x * 64;
  int uv = blockIdx.y >> 1;
  int colbase = (blockIdx.y & 1) * 128;
  const unsigned short* Wh = uv ? Wbh : Wuh;
  const unsigned short* Wl = uv ? Wbl : Wul;
  float* Out = uv ? V : U;
  size_t aoff = (size_t)(rowbase + w*16 + m)*DD;
  int srow = tid >> 1;
  int sseg = (tid & 1) * 2;
  f32x4 acc[8];
  #pragma unroll
  for (int t = 0; t < 8; t++) acc[t] = (f32x4){0.f, 0.f, 0.f, 0.f};
  #pragma unroll 1
  for (int c = 0; c < 8; c++) {
    int k0 = c*32 + quad*8;
    bf16x8 ah = *(const bf16x8*)(xhi + aoff + k0);
    bf16x8 al = *(const bf16x8*)(xlo + aoff + k0);
    const float* wrh = (const float*)(Wh + (size_t)(colbase + srow)*DD + c*32);
    const float* wrl = (const float*)(Wl + (size_t)(colbase + srow)*DD + c*32);
    float4 wh0 = *(const float4*)(wrh + sseg*4);
    float4 wh1 = *(const float4*)(wrh + (sseg+1)*4);
    float4 wl0 = *(const float4*)(wrl + sseg*4);
    float4 wl1 = *(const float4*)(wrl + (sseg+1)*4);
    __syncthreads();
    *(float4*)&wSh[srow*18 + sseg*4]     = wh0;
    *(float4*)&wSh[srow*18 + (sseg+1)*4] = wh1;
    *(float4*)&wSl[srow*18 + sseg*4]     = wl0;
    *(float4*)&wSl[srow*18 + (sseg+1)*4] = wl1;
    __syncthreads();
    #pragma unroll
    for (int nt = 0; nt < 8; nt++) {
      bf16x8 bh = *(const bf16x8*)&wSh[(nt*16 + m)*18 + quad*4];
      bf16x8 bl = *(const bf16x8*)&wSl[(nt*16 + m)*18 + quad*4];
      acc[nt] = __builtin_amdgcn_mfma_f32_16x16x32_bf16(ah, bh, acc[nt], 0, 0, 0);
      acc[nt] = __builtin_amdgcn_mfma_f32_16x16x32_bf16(ah, bl, acc[nt], 0, 0, 0);
      acc[nt] = __builtin_amdgcn_mfma_f32_16x16x32_bf16(al, bh, acc[nt], 0, 0, 0);
    }
  }
  #pragma unroll
  for (int nt = 0; nt < 8; nt++) {
    int col = colbase + nt*16 + m;
    #pragma unroll
    for (int r = 0; r < 4; r++) {
      int row = rowbase + w*16 + quad*4 + r;
      Out[(size_t)row*DD + col] = acc[nt][r];
    }
  }
}

// ---------------- kNN via split-bf16 MFMA, LDS-staged j-rows, register-hoisted A
// (R20/R23-proven).
__global__ __launch_bounds__(256) void knnk(
    const unsigned short* __restrict__ xhi, const unsigned short* __restrict__ xlo,
    const float* __restrict__ sq,
    float* __restrict__ pdg, int* __restrict__ pjg)
{
  __shared__ float smem[4736];
  float* jh = smem;                 // 64 rows x 36 floats
  float* jl = smem + 2304;
  float (*dt)[65] = (float(*)[65])smem;
  float* sqI = smem + 4608;
  float* sqJ = smem + 4672;
  int tid = threadIdx.x;
  int q  = blockIdx.x & 3;
  int it = (blockIdx.x >> 2) & 31;
  int bb = blockIdx.x >> 7;
  int ibase = it * 64;
  const unsigned short* xhb = xhi + (size_t)bb*NN*DD;
  const unsigned short* xlb = xlo + (size_t)bb*NN*DD;
  const float* sqb = sq + (size_t)bb*NN;
  int w = tid >> 6, lane = tid & 63;
  int m = lane & 15, quad = lane >> 4;
  int selrow = tid & 63, selseg = tid >> 6;
  size_t aoff = (size_t)(ibase + w*16 + m)*DD;
  int srow = tid >> 2;
  int sseg = tid & 3;
  bf16x8 ahr[8], alr[8];
  #pragma unroll
  for (int c = 0; c < 8; c++) {
    int k0 = c*32 + quad*8;
    ahr[c] = *(const bf16x8*)(xhb + aoff + k0);
    alr[c] = *(const bf16x8*)(xlb + aoff + k0);
  }
  float bd[8]; int bj[8];
  #pragma unroll
  for (int s = 0; s < 8; s++) { bd[s] = 3.4e38f; bj[s] = 0; }
  if (tid < 64) sqI[tid] = sqb[ibase + tid];
  #pragma unroll 1
  for (int jt = 0; jt < 8; jt++) {
    int jbase = q*512 + jt*64;
    if (tid < 64) sqJ[tid] = sqb[jbase + tid];
    f32x4 acc[4];
    #pragma unroll
    for (int t = 0; t < 4; t++) acc[t] = (f32x4){0.f, 0.f, 0.f, 0.f};
    #pragma unroll
    for (int c2 = 0; c2 < 4; c2++) {
      size_t gb = (size_t)(jbase + srow)*DD + c2*64;
      float4 h0 = *(const float4*)((const float*)(xhb + gb) + sseg*4);
      float4 h1 = *(const float4*)((const float*)(xhb + gb) + (sseg+4)*4);
      float4 l0 = *(const float4*)((const float*)(xlb + gb) + sseg*4);
      float4 l1 = *(const float4*)((const float*)(xlb + gb) + (sseg+4)*4);
      __syncthreads();
      *(float4*)&jh[srow*36 + sseg*4]     = h0;
      *(float4*)&jh[srow*36 + (sseg+4)*4] = h1;
      *(float4*)&jl[srow*36 + sseg*4]     = l0;
      *(float4*)&jl[srow*36 + (sseg+4)*4] = l1;
      __syncthreads();
      #pragma unroll
      for (int kk = 0; kk < 2; kk++) {
        bf16x8 ah = ahr[c2*2 + kk];
        bf16x8 al = alr[c2*2 + kk];
        int lofs = kk*16 + quad*4;
        #pragma unroll
        for (int nt = 0; nt < 4; nt++) {
          int r = nt*16 + m;
          bf16x8 bh = *(const bf16x8*)&jh[r*36 + lofs];
          bf16x8 bl = *(const bf16x8*)&jl[r*36 + lofs];
          acc[nt] = __builtin_amdgcn_mfma_f32_16x16x32_bf16(ah, bh, acc[nt], 0, 0, 0);
          acc[nt] = __builtin_amdgcn_mfma_f32_16x16x32_bf16(ah, bl, acc[nt], 0, 0, 0);
          acc[nt] = __builtin_amdgcn_mfma_f32_16x16x32_bf16(al, bh, acc[nt], 0, 0, 0);
        }
      }
    }
    __syncthreads();
    #pragma unroll
    for (int nt = 0; nt < 4; nt++) {
      int col = nt*16 + m;
      float sj = sqJ[col];
      #pragma unroll
      for (int r = 0; r < 4; r++) {
        int rowl = w*16 + quad*4 + r;
        dt[rowl][col] = sqI[rowl] + sj - 2.f*acc[nt][r];
      }
    }
    __syncthreads();
    int cb = selseg*16;
    #pragma unroll
    for (int s = 0; s < 16; s++) {
      float dv = dt[selrow][cb + s];
      if (dv < bd[7]) {
        bd[7] = dv; bj[7] = jbase + cb + s;
        #pragma unroll
        for (int t = 7; t >= 1; t--) {
          if (bd[t] < bd[t-1]) {
            float td = bd[t]; bd[t] = bd[t-1]; bd[t-1] = td;
            int   tj = bj[t]; bj[t] = bj[t-1]; bj[t-1] = tj;
          }
        }
      }
    }
  }
  __syncthreads();
  float* pdl = &smem[0];
  int*   pjl = (int*)&smem[2048];
  #pragma unroll
  for (int s = 0; s < 8; s++) {
    pdl[tid*8 + s] = bd[s];
    pjl[tid*8 + s] = bj[s];
  }
  __syncthreads();
  if (tid < 64) {
    float md[8]; int mj[8];
    #pragma unroll
    for (int s = 0; s < 8; s++) { md[s] = 3.4e38f; mj[s] = 0; }
    #pragma unroll 1
    for (int g = 0; g < 4; g++) {
      int base = (g*64 + tid)*8;
      #pragma unroll
      for (int s = 0; s < 8; s++) {
        float dv = pdl[base + s];
        if (dv < md[7]) {
          md[7] = dv; mj[7] = pjl[base + s];
          #pragma unroll
          for (int t = 7; t >= 1; t--) {
            if (md[t] < md[t-1]) {
              float td = md[t]; md[t] = md[t-1]; md[t-1] = td;
              int   tj = mj[t]; mj[t] = mj[t-1]; mj[t-1] = tj;
            }
          }
        }
      }
    }
    size_t gbase = ((size_t)(bb*NN + ibase + tid))*32 + (size_t)q*8;
    #pragma unroll
    for (int s = 0; s < 8; s++) {
      pdg[gbase + s] = md[s];
      pjg[gbase + s] = bb*NN + mj[s];
    }
  }
}

// ---------------- merge 4 quarter-lists per point -> final 8 neighbor indices
__global__ __launch_bounds__(256) void knnmerge(const float* __restrict__ pdg, const int* __restrict__ pjg,
                                                int* __restrict__ idxg)
{
  int p = blockIdx.x*256 + threadIdx.x;
  float md[8]; int mj[8];
  #pragma unroll
  for (int s = 0; s < 8; s++) { md[s] = 3.4e38f; mj[s] = 0; }
  size_t base = (size_t)p*32;
  #pragma unroll 1
  for (int s = 0; s < 32; s++) {
    float dv = pdg[base + s];
    if (dv < md[7]) {
      md[7] = dv; mj[7] = pjg[base + s];
      #pragma unroll
      for (int t = 7; t >= 1; t--) {
        if (md[t] < md[t-1]) {
          float td = md[t]; md[t] = md[t-1]; md[t-1] = td;
          int   tj = mj[t]; mj[t] = mj[t-1]; mj[t-1] = tj;
        }
      }
    }
  }
  #pragma unroll
  for (int s = 0; s < 8; s++) idxg[(size_t)p*8 + s] = mj[s];
}

// ---------------- BN1 stats v2: float4 gathers, 4 point-groups, LDS cross-group reduce.
// Same per-channel fp32 accumulation math; 4x fewer issued loads, 4 gather streams in flight.
__global__ __launch_bounds__(256) void bn1stats(const float* __restrict__ u, const float* __restrict__ v,
    const int* __restrict__ idxg, const float* __restrict__ b1, float* __restrict__ stats)
{
  __shared__ int jL[128];
  __shared__ float redS[4][256];
  __shared__ float redQ[4][256];
  int tid = threadIdx.x;
  int g = tid >> 6;               // point-group 0..3
  int cq = (tid & 63) * 4;        // channel quad base
  int n0 = blockIdx.x * 16;
  if (tid < 128) jL[tid] = idxg[(size_t)n0*8 + tid];
  __syncthreads();
  float4 b4 = *(const float4*)&b1[cq];
  float4 s = make_float4(0.f, 0.f, 0.f, 0.f);
  float4 q = make_float4(0.f, 0.f, 0.f, 0.f);
  #pragma unroll 1
  for (int n = 0; n < 4; n++) {
    int pl = g*4 + n;
    float4 u4 = *(const float4*)&u[(size_t)(n0 + pl)*DD + cq];
    float4 ub = make_float4(u4.x + b4.x, u4.y + b4.y, u4.z + b4.z, u4.w + b4.w);
    #pragma unroll
    for (int e = 0; e < 8; e++) {
      int j = jL[pl*8 + e];
      float4 v4 = *(const float4*)&v[(size_t)j*DD + cq];
      float h0 = fmaxf(ub.x + v4.x, 0.f);
      float h1 = fmaxf(ub.y + v4.y, 0.f);
      float h2 = fmaxf(ub.z + v4.z, 0.f);
      float h3 = fmaxf(ub.w + v4.w, 0.f);
      s.x += h0; s.y += h1; s.z += h2; s.w += h3;
      q.x += h0*h0; q.y += h1*h1; q.z += h2*h2; q.w += h3*h3;
    }
  }
  *(float4*)&redS[g][cq] = s;
  *(float4*)&redQ[g][cq] = q;
  __syncthreads();
  int c = tid;
  float ts = redS[0][c] + redS[1][c] + redS[2][c] + redS[3][c];
  float tq = redQ[0][c] + redQ[1][c] + redQ[2][c] + redQ[3][c];
  int row = blockIdx.x & (NSH - 1);
  atomicAdd(&stats[row*1024 + c], ts);
  atomicAdd(&stats[row*1024 + 256 + c], tq);
}

// ---------------- fold BN1 into layer-2 weights; emit TRANSPOSED bf16 weights
__global__ __launch_bounds__(256) void prep2(const float* __restrict__ stats, const float* __restrict__ g1,
    const float* __restrict__ be1, const float* __restrict__ gW2, const float* __restrict__ gb2,
    unsigned short* __restrict__ w2bf, float* __restrict__ biasp)
{
  __shared__ float s1L[256], t1L[256];
  int tid = threadIdx.x;
  const float inv = 1.f / (float)NEDGE;
  float sm = 0.f, sq2 = 0.f;
  #pragma unroll 1
  for (int r = 0; r < NSH; r++) {
    sm  += stats[r*1024 + tid];
    sq2 += stats[r*1024 + 256 + tid];
  }
  float m = sm * inv;
  float var = sq2*inv - m*m;
  float s1 = g1[tid] / sqrtf(var + BN_EPS);
  s1L[tid] = s1; t1L[tid] = be1[tid] - m*s1;
  __syncthreads();
  float bacc = gb2[tid];
  for (int k = 0; k < DD; k++) {
    float w = gW2[k*DD + tid];
    w2bf[(size_t)tid*DD + k] = f2bf(s1L[k]*w);
    bacc += t1L[k]*w;
  }
  biasp[tid] = bacc;
}

// ---------------- edge GEMM v2: col-split x2 + LDS-staged u-rows (8 distinct rows/block,
// previously gathered 8x redundantly) with b1 pre-added; v-gathers remain global.
__global__ __launch_bounds__(256) void edgek(
    const float* __restrict__ u, const float* __restrict__ v, const int* __restrict__ idxg,
    const float* __restrict__ b1, const unsigned short* __restrict__ w2bf,
    const float* __restrict__ biasp,
    float* __restrict__ pmaxs, float* __restrict__ pmins, float* __restrict__ stats)
{
  __shared__ float wS[128*18];     // 9 KB
  __shared__ float uB[8*256];      // 8 KB: u-rows + b1
  int tid = threadIdx.x;
  int w = tid >> 6, lane = tid & 63;
  int m = lane & 15, quad = lane >> 4;
  int rowbase = blockIdx.x * 64;
  int colbase = blockIdx.y * 128;
  // stage uB[r][c] = u[(rowbase>>3)+r][c] + b1[c]
  {
    int r = tid >> 5;              // 0..7
    int cc = (tid & 31) * 8;       // 0..248
    const float* ur = u + ((size_t)(rowbase >> 3) + r)*DD + cc;
    float4 a0 = *(const float4*)ur;
    float4 a1 = *(const float4*)(ur + 4);
    float4 b0 = *(const float4*)(b1 + cc);
    float4 b1v = *(const float4*)(b1 + cc + 4);
    *(float4*)&uB[r*256 + cc]     = make_float4(a0.x+b0.x, a0.y+b0.y, a0.z+b0.z, a0.w+b0.w);
    *(float4*)&uB[r*256 + cc + 4] = make_float4(a1.x+b1v.x, a1.y+b1v.y, a1.z+b1v.z, a1.w+b1v.w);
  }
  int edge = rowbase + w*16 + m;
  int iul = (w*16 + m) >> 3;       // local u-row 0..7
  int jv = idxg[edge];
  const float* vrow = v + (size_t)jv*DD;
  int srow = tid >> 1;
  int sseg = (tid & 1) * 2;
  f32x4 acc[8];
  #pragma unroll
  for (int t = 0; t < 8; t++) acc[t] = (f32x4){0.f, 0.f, 0.f, 0.f};
  __syncthreads();                 // uB visible
  #pragma unroll 1
  for (int c = 0; c < 8; c++) {
    int k0 = c*32 + quad*8;
    float4 va = *(const float4*)(vrow + k0);
    float4 vb = *(const float4*)(vrow + k0 + 4);
    float4 ua = *(const float4*)&uB[iul*256 + k0];
    float4 ub = *(const float4*)&uB[iul*256 + k0 + 4];
    const float* wrow = (const float*)(w2bf + (size_t)(colbase + srow)*DD + c*32);
    float4 wreg0 = *(const float4*)(wrow + sseg*4);
    float4 wreg1 = *(const float4*)(wrow + (sseg+1)*4);
    float h0 = fmaxf(ua.x+va.x, 0.f);
    float h1 = fmaxf(ua.y+va.y, 0.f);
    float h2 = fmaxf(ua.z+va.z, 0.f);
    float h3 = fmaxf(ua.w+va.w, 0.f);
    float h4 = fmaxf(ub.x+vb.x, 0.f);
    float h5 = fmaxf(ub.y+vb.y, 0.f);
    float h6 = fmaxf(ub.z+vb.z, 0.f);
    float h7 = fmaxf(ub.w+vb.w, 0.f);
    union { bf16x8 v8; unsigned short s[8]; } af;
    af.s[0] = f2bf(h0); af.s[1] = f2bf(h1); af.s[2] = f2bf(h2); af.s[3] = f2bf(h3);
    af.s[4] = f2bf(h4); af.s[5] = f2bf(h5); af.s[6] = f2bf(h6); af.s[7] = f2bf(h7);
    __syncthreads();
    *(float4*)&wS[srow*18 + sseg*4]     = wreg0;
    *(float4*)&wS[srow*18 + (sseg+1)*4] = wreg1;
    __syncthreads();
    #pragma unroll
    for (int nt = 0; nt < 8; nt++) {
      bf16x8 bf = *(const bf16x8*)&wS[(nt*16 + m)*18 + quad*4];
      acc[nt] = __builtin_amdgcn_mfma_f32_16x16x32_bf16(af.v8, bf, acc[nt], 0, 0, 0);
    }
  }
  float* redS = wS;
  float* redQ = wS + 512;
  float* redM = wS + 1024;
  float* redN = wS + 1536;
  float mxr[8], mnr[8], ssr[8], sqr[8];
  #pragma unroll
  for (int nt = 0; nt < 8; nt++) {
    int col = nt*16 + m;
    float bp = biasp[colbase + col];
    float r0 = fmaxf(acc[nt].x + bp, 0.f);
    float r1 = fmaxf(acc[nt].y + bp, 0.f);
    float r2 = fmaxf(acc[nt].z + bp, 0.f);
    float r3 = fmaxf(acc[nt].w + bp, 0.f);
    float mx = fmaxf(fmaxf(r0, r1), fmaxf(r2, r3));
    float mn = fminf(fminf(r0, r1), fminf(r2, r3));
    float ss = r0 + r1 + r2 + r3;
    float s2 = r0*r0 + r1*r1 + r2*r2 + r3*r3;
    mx = fmaxf(mx, __shfl_xor(mx, 16, 64));
    mx = fmaxf(mx, __shfl_xor(mx, 32, 64));
    mn = fminf(mn, __shfl_xor(mn, 16, 64));
    mn = fminf(mn, __shfl_xor(mn, 32, 64));
    ss += __shfl_xor(ss, 16, 64);
    ss += __shfl_xor(ss, 32, 64);
    s2 += __shfl_xor(s2, 16, 64);
    s2 += __shfl_xor(s2, 32, 64);
    mxr[nt] = mx; mnr[nt] = mn; ssr[nt] = ss; sqr[nt] = s2;
  }
  __syncthreads();
  if (quad == 0) {
    #pragma unroll
    for (int nt = 0; nt < 8; nt++) {
      int col = nt*16 + m;
      redS[w*128 + col] = ssr[nt];
      redQ[w*128 + col] = sqr[nt];
      redM[w*128 + col] = mxr[nt];
      redN[w*128 + col] = mnr[nt];
    }
  }
  __syncthreads();
  if (tid < 128) {
    float ts  = redS[tid] + redS[128+tid] + redS[256+tid] + redS[384+tid];
    float tq  = redQ[tid] + redQ[128+tid] + redQ[256+tid] + redQ[384+tid];
    float mxc = fmaxf(fmaxf(redM[tid], redM[128+tid]), fmaxf(redM[256+tid], redM[384+tid]));
    float mnc = fminf(fminf(redN[tid], redN[128+tid]), fminf(redN[256+tid], redN[384+tid]));
    int row = blockIdx.x & (NSH - 1);
    atomicAdd(&stats[row*1024 + 512 + colbase + tid], ts);
    atomicAdd(&stats[row*1024 + 768 + colbase + tid], tq);
    int b  = blockIdx.x >> 8;
    int sh = blockIdx.x & (PSH - 1);
    atomicMax((int*)&pmaxs[((size_t)sh*BB + b)*DD + colbase + tid], __float_as_int(mxc));
    atomicMin((int*)&pmins[((size_t)sh*BB + b)*DD + colbase + tid], __float_as_int(mnc));
  }
}

// ---------------- final: one block per batch (R18-proven)
__global__ __launch_bounds__(256) void finalk(const float* __restrict__ pmaxs, const float* __restrict__ pmins,
    const float* __restrict__ stats, const float* __restrict__ g2, const float* __restrict__ be2,
    const float* __restrict__ W1, const float* __restrict__ b1,
    const float* __restrict__ W2, const float* __restrict__ b2,
    float* __restrict__ out)
{
  __shared__ float pl[256];
  __shared__ float hl[256];
  __shared__ float red[4];
  int c = threadIdx.x;
  int b = blockIdx.x;
  const float inv = 1.f / (float)NEDGE;
  float sm = 0.f, sq2 = 0.f;
  #pragma unroll 1
  for (int r = 0; r < NSH; r++) {
    sm  += stats[r*1024 + 512 + c];
    sq2 += stats[r*1024 + 768 + c];
  }
  float m = sm * inv;
  float var = sq2*inv - m*m;
  float s2 = g2[c] / sqrtf(var + BN_EPS);
  float t2 = be2[c] - m*s2;
  float mx = -3.4e38f, mn = 3.4e38f;
  #pragma unroll 1
  for (int s = 0; s < PSH; s++) {
    mx = fmaxf(mx, pmaxs[((size_t)s*BB + b)*DD + c]);
    mn = fminf(mn, pmins[((size_t)s*BB + b)*DD + c]);
  }
  pl[c] = (s2 >= 0.f) ? s2*mx + t2 : s2*mn + t2;
  __syncthreads();
  float h = b1[c];
  #pragma unroll 4
  for (int k = 0; k < 256; k++) h += pl[k]*W1[k*256 + c];
  hl[c] = fmaxf(h, 0.f);
  __syncthreads();
  float o = b2[c];
  #pragma unroll 4
  for (int k = 0; k < 256; k++) o += hl[k]*W2[k*256 + c];
  o = fmaxf(o, 0.f);
  float s = o*o;
  #pragma unroll
  for (int mm = 1; mm <= 32; mm <<= 1) s += __shfl_xor(s, mm, 64);
  if ((c & 63) == 0) red[c >> 6] = s;
  __syncthreads();
  float tot = red[0] + red[1] + red[2] + red[3];
  out[b*256 + c] = o / fmaxf(sqrtf(tot), 1e-12f);
}

extern "C" void kernel_launch(void* const* d_in, const int* in_sizes, int n_in,
                              void* d_out, int out_size, void* d_ws, size_t ws_size,
                              hipStream_t stream) {
  (void)in_sizes; (void)n_in; (void)out_size; (void)ws_size;
  const int*   cls       = (const int*)  d_in[0];
  const float* colors    = (const float*)d_in[1];
  const float* positions = (const float*)d_in[2];
  const float* ctab      = (const float*)d_in[3];
  const float* pW1 = (const float*)d_in[4];
  const float* pb1 = (const float*)d_in[5];
  const float* pW2 = (const float*)d_in[6];
  const float* pb2 = (const float*)d_in[7];
  const float* cW1 = (const float*)d_in[8];
  const float* cb1 = (const float*)d_in[9];
  const float* cW2 = (const float*)d_in[10];
  const float* cb2 = (const float*)d_in[11];
  const float* mW  = (const float*)d_in[12];
  const float* mb  = (const float*)d_in[13];
  const float* gW1 = (const float*)d_in[14];
  const float* gb1 = (const float*)d_in[15];
  const float* gg1 = (const float*)d_in[16];
  const float* gbe1= (const float*)d_in[17];
  const float* gW2 = (const float*)d_in[18];
  const float* gb2 = (const float*)d_in[19];
  const float* gg2 = (const float*)d_in[20];
  const float* gbe2= (const float*)d_in[21];
  const float* lW1 = (const float*)d_in[22];
  const float* lb1 = (const float*)d_in[23];
  const float* lW2 = (const float*)d_in[24];
  const float* lb2 = (const float*)d_in[25];
  float* out = (float*)d_out;

  float* wsf   = (float*)d_ws;
  unsigned short* feathi = (unsigned short*)(wsf + OFF_FEAT);
  unsigned short* featlo = feathi + (size_t)NPTS*768;
  float* sq    = wsf + OFF_SQ;
  int*   idxg  = (int*)(wsf + OFF_IDX);
  float* u     = wsf + OFF_U;
  float* v     = wsf + OFF_V;
  unsigned short* w2bf = (unsigned short*)(wsf + OFF_W2BF);
  float* biasp = wsf + OFF_BIASP;
  unsigned short* xhi = (unsigned short*)(wsf + OFF_XHI);
  unsigned short* xlo = (unsigned short*)(wsf + OFF_XLO);
  unsigned short* mwh = (unsigned short*)(wsf + OFF_MWH);
  unsigned short* mwl = (unsigned short*)(wsf + OFF_MWL);
  unsigned short* Wuh = (unsigned short*)(wsf + OFF_WUH);
  unsigned short* Wul = (unsigned short*)(wsf + OFF_WUL);
  unsigned short* Wbh = (unsigned short*)(wsf + OFF_WBH);
  unsigned short* Wbl = (unsigned short*)(wsf + OFF_WBL);
  float* stats = wsf + OFF_STATS;
  float* pmaxs = wsf + OFF_PMAXS;
  float* pmins = wsf + OFF_PMINS;
  // partial kNN buffers overlay feathi/featlo region (dead after gemm768)
  float* pdg   = wsf + OFF_FEAT;
  int*   pjg   = (int*)(wsf + OFF_FEAT + (size_t)NPTS*32);

  // stats + pmaxs + sq are contiguous -> one zero memset
  hipMemsetAsync(stats, 0, (NSH*1024 + PSH*BB*DD + NPTS)*sizeof(float), stream);
  hipMemsetAsync(pmins, 0x7f, PSH*BB*DD*sizeof(float), stream);   // ~3.39e38f

  prepk<<<4096 + 768 + 256, 256, 0, stream>>>(cls, colors, positions, ctab,
                                              pW1, pb1, pW2, pb2, cW1, cb1, cW2, cb2,
                                              feathi, featlo, mW, mwh, mwl,
                                              gW1, Wuh, Wul, Wbh, Wbl);
  gemm768<<<dim3(NPTS/64, 2), 256, 0, stream>>>(feathi, featlo, mwh, mwl, mb, sq, xhi, xlo);
  knnk<<<BB*32*4, 256, 0, stream>>>(xhi, xlo, sq, pdg, pjg);
  knnmerge<<<NPTS/256, 256, 0, stream>>>(pdg, pjg, idxg);
  gemmuv<<<dim3(NPTS/64, 4), 256, 0, stream>>>(xhi, xlo, Wuh, Wul, Wbh, Wbl, u, v);
  bn1stats<<<NPTS/16, 256, 0, stream>>>(u, v, idxg, gb1, stats);
  prep2<<<1, 256, 0, stream>>>(stats, gg1, gbe1, gW2, gb2, w2bf, biasp);
  edgek<<<dim3(NEDGE/64, 2), 256, 0, stream>>>(u, v, idxg, gb1, w2bf, biasp, pmaxs, pmins, stats);
  finalk<<<BB, 256, 0, stream>>>(pmaxs, pmins, stats, gg2, gbe2, lW1, lb1, lW2, lb2, out);
}

// Round 29
// 502.486 us; speedup vs baseline: 1.2058x; 1.0131x over previous
//
#include <hip/hip_runtime.h>
#include <math.h>

#define BB 8
#define NN 2048
#define DD 256
#define KNN 8
#define NPTS (BB*NN)        // 16384
#define NEDGE (NPTS*KNN)    // 131072
#define BN_EPS 1e-5f
#define NSH 64              // shadow copies for BN stats accumulation
#define PSH 32              // shadow copies for pooled max/min

// ---- workspace layout (float offsets) ----
#define OFF_X      0
#define OFF_FEAT   (OFF_X + NPTS*DD)          // region holds feathi+featlo (ushort), pdg/pjg overlay
#define OFF_STATS  (OFF_FEAT + NPTS*3*DD)     // NSH x 1024
#define OFF_PMAXS  (OFF_STATS + NSH*1024)     // PSH x BB x 256
#define OFF_SQ     (OFF_PMAXS + PSH*BB*DD)    // NPTS
#define OFF_PMINS  (OFF_SQ + NPTS)            // PSH x BB x 256
#define OFF_IDX    (OFF_PMINS + PSH*BB*DD)
#define OFF_U      (OFF_IDX + NEDGE)
#define OFF_V      (OFF_U + NPTS*DD)
#define OFF_W2BF   (OFF_V + NPTS*DD)          // 256x256 ushort
#define OFF_BIASP  (OFF_W2BF + 32768)
#define OFF_XHI    (OFF_BIASP + DD)           // NPTS x 256 ushort
#define OFF_XLO    (OFF_XHI + NPTS*DD/2)      // NPTS x 256 ushort
#define OFF_MWH    (OFF_XLO + NPTS*DD/2)      // 256x768 ushort (transposed)
#define OFF_MWL    (OFF_MWH + 98304)
#define OFF_WUH    (OFF_MWL + 98304)          // 4 uv weight tables, 256x256 ushort each
#define OFF_WUL    (OFF_WUH + 32768)
#define OFF_WBH    (OFF_WUL + 32768)
#define OFF_WBL    (OFF_WBH + 32768)

typedef __attribute__((ext_vector_type(8))) short bf16x8;
typedef __attribute__((ext_vector_type(4))) float f32x4;

__device__ __forceinline__ unsigned short f2bf(float f) {
  unsigned int u = __float_as_uint(f);
  u += 0x7FFF + ((u >> 16) & 1);   // round to nearest even
  return (unsigned short)(u >> 16);
}
__device__ __forceinline__ float bf2f(unsigned short h) {
  return __uint_as_float((unsigned int)h << 16);
}

// ---------------- merged prep: featurize (bx<4096) | prep_mw (bx<4864) | prep_uvw.
__global__ __launch_bounds__(256) void prepk(
    const int* __restrict__ cls, const float* __restrict__ colors, const float* __restrict__ positions,
    const float* __restrict__ ctab,
    const float* __restrict__ pW1, const float* __restrict__ pb1, const float* __restrict__ pW2, const float* __restrict__ pb2,
    const float* __restrict__ cW1, const float* __restrict__ cb1, const float* __restrict__ cW2, const float* __restrict__ cb2,
    unsigned short* __restrict__ feathi, unsigned short* __restrict__ featlo,
    const float* __restrict__ mW,
    unsigned short* __restrict__ mwh, unsigned short* __restrict__ mwl,
    const float* __restrict__ gW1,
    unsigned short* __restrict__ Wuh, unsigned short* __restrict__ Wul,
    unsigned short* __restrict__ Wbh, unsigned short* __restrict__ Wbl)
{
  __shared__ float wbuf[4][64];
  int bx = blockIdx.x;
  int tid = threadIdx.x;
  if (bx < 4096) {
    int wv = tid >> 6, lane = tid & 63;
    int p = bx*4 + wv;
    if (lane < 32) {
      float c0 = colors[p*3+0], c1 = colors[p*3+1], c2 = colors[p*3+2];
      wbuf[wv][lane] = fmaxf(c0*cW1[lane] + c1*cW1[32+lane] + c2*cW1[64+lane] + cb1[lane], 0.f);
    } else {
      int l = lane - 32;
      float q0 = positions[p*3+0], q1 = positions[p*3+1], q2 = positions[p*3+2];
      wbuf[wv][32+l] = fmaxf(q0*pW1[l] + q1*pW1[32+l] + q2*pW1[64+l] + pb1[l], 0.f);
    }
    __syncthreads();
    int c = lane*4;
    float4 ce4 = *(const float4*)&ctab[(size_t)cls[p]*DD + c];
    float4 col4 = *(const float4*)&cb2[c];
    float4 pos4 = *(const float4*)&pb2[c];
    #pragma unroll
    for (int k = 0; k < 32; k++) {
      float ch = wbuf[wv][k], ph = wbuf[wv][32+k];
      float4 cw = *(const float4*)&cW2[k*DD + c];
      float4 pw = *(const float4*)&pW2[k*DD + c];
      col4.x += ch*cw.x; col4.y += ch*cw.y; col4.z += ch*cw.z; col4.w += ch*cw.w;
      pos4.x += ph*pw.x; pos4.y += ph*pw.y; pos4.z += ph*pw.z; pos4.w += ph*pw.w;
    }
    col4.x = fmaxf(col4.x, 0.f); col4.y = fmaxf(col4.y, 0.f);
    col4.z = fmaxf(col4.z, 0.f); col4.w = fmaxf(col4.w, 0.f);
    pos4.x = fmaxf(pos4.x, 0.f); pos4.y = fmaxf(pos4.y, 0.f);
    pos4.z = fmaxf(pos4.z, 0.f); pos4.w = fmaxf(pos4.w, 0.f);
    float sce  = ce4.x*ce4.x + ce4.y*ce4.y + ce4.z*ce4.z + ce4.w*ce4.w;
    float scol = col4.x*col4.x + col4.y*col4.y + col4.z*col4.z + col4.w*col4.w;
    float spos = pos4.x*pos4.x + pos4.y*pos4.y + pos4.z*pos4.z + pos4.w*pos4.w;
    #pragma unroll
    for (int m = 1; m <= 32; m <<= 1) {
      sce  += __shfl_xor(sce,  m, 64);
      scol += __shfl_xor(scol, m, 64);
      spos += __shfl_xor(spos, m, 64);
    }
    float ice = 1.f / fmaxf(sqrtf(sce),  1e-12f);
    float icl = 1.f / fmaxf(sqrtf(scol), 1e-12f);
    float ips = 1.f / fmaxf(sqrtf(spos), 1e-12f);
    float o[3][4] = {
      {ce4.x*ice,  ce4.y*ice,  ce4.z*ice,  ce4.w*ice},
      {col4.x*icl, col4.y*icl, col4.z*icl, col4.w*icl},
      {pos4.x*ips, pos4.y*ips, pos4.z*ips, pos4.w*ips}
    };
    #pragma unroll
    for (int sgm = 0; sgm < 3; sgm++) {
      unsigned short h[4], l[4];
      #pragma unroll
      for (int cc = 0; cc < 4; cc++) {
        h[cc] = f2bf(o[sgm][cc]);
        l[cc] = f2bf(o[sgm][cc] - bf2f(h[cc]));
      }
      size_t off = (size_t)p*768 + sgm*256 + c;
      *(uint2*)&feathi[off] = make_uint2((unsigned)h[0] | ((unsigned)h[1] << 16),
                                         (unsigned)h[2] | ((unsigned)h[3] << 16));
      *(uint2*)&featlo[off] = make_uint2((unsigned)l[0] | ((unsigned)l[1] << 16),
                                         (unsigned)l[2] | ((unsigned)l[3] << 16));
    }
  } else if (bx < 4096 + 768) {
    int k = bx - 4096;
    int n = tid;
    float wgt = mW[(size_t)k*DD + n];
    unsigned short h = f2bf(wgt);
    mwh[(size_t)n*768 + k] = h;
    mwl[(size_t)n*768 + k] = f2bf(wgt - bf2f(h));
  } else {
    int k = bx - (4096 + 768);
    int n = tid;
    float t = gW1[(size_t)k*DD + n];
    float b = gW1[(size_t)(k + DD)*DD + n];
    float wu = t - b;
    unsigned short uh = f2bf(wu), bh = f2bf(b);
    Wuh[(size_t)n*DD + k] = uh;
    Wul[(size_t)n*DD + k] = f2bf(wu - bf2f(uh));
    Wbh[(size_t)n*DD + k] = bh;
    Wbl[(size_t)n*DD + k] = f2bf(b - bf2f(bh));
  }
}

// ---------------- merge GEMM via split-bf16 MFMA, col-split x2 (R24-proven; no x write)
__global__ __launch_bounds__(256) void gemm768(
    const unsigned short* __restrict__ feathi, const unsigned short* __restrict__ featlo,
    const unsigned short* __restrict__ mwh, const unsigned short* __restrict__ mwl,
    const float* __restrict__ mb,
    float* __restrict__ sqo,
    unsigned short* __restrict__ xhi, unsigned short* __restrict__ xlo)
{
  __shared__ float wSh[128*18];
  __shared__ float wSl[128*18];
  int tid = threadIdx.x;
  int w = tid >> 6, lane = tid & 63;
  int m = lane & 15, quad = lane >> 4;
  int rowbase = blockIdx.x * 64;
  int colbase = blockIdx.y * 128;
  size_t aoff = (size_t)(rowbase + w*16 + m)*768;
  int srow = tid >> 1;
  int sseg = (tid & 1) * 2;
  f32x4 acc[8];
  #pragma unroll
  for (int t = 0; t < 8; t++) acc[t] = (f32x4){0.f, 0.f, 0.f, 0.f};
  #pragma unroll 1
  for (int c = 0; c < 24; c++) {
    int k0 = c*32 + quad*8;
    bf16x8 ah = *(const bf16x8*)(feathi + aoff + k0);
    bf16x8 al = *(const bf16x8*)(featlo + aoff + k0);
    const float* wrh = (const float*)(mwh + (size_t)(colbase + srow)*768 + c*32);
    const float* wrl = (const float*)(mwl + (size_t)(colbase + srow)*768 + c*32);
    float4 wh0 = *(const float4*)(wrh + sseg*4);
    float4 wh1 = *(const float4*)(wrh + (sseg+1)*4);
    float4 wl0 = *(const float4*)(wrl + sseg*4);
    float4 wl1 = *(const float4*)(wrl + (sseg+1)*4);
    __syncthreads();
    *(float4*)&wSh[srow*18 + sseg*4]     = wh0;
    *(float4*)&wSh[srow*18 + (sseg+1)*4] = wh1;
    *(float4*)&wSl[srow*18 + sseg*4]     = wl0;
    *(float4*)&wSl[srow*18 + (sseg+1)*4] = wl1;
    __syncthreads();
    #pragma unroll
    for (int nt = 0; nt < 8; nt++) {
      bf16x8 bh = *(const bf16x8*)&wSh[(nt*16 + m)*18 + quad*4];
      bf16x8 bl = *(const bf16x8*)&wSl[(nt*16 + m)*18 + quad*4];
      acc[nt] = __builtin_amdgcn_mfma_f32_16x16x32_bf16(ah, bh, acc[nt], 0, 0, 0);
      acc[nt] = __builtin_amdgcn_mfma_f32_16x16x32_bf16(ah, bl, acc[nt], 0, 0, 0);
      acc[nt] = __builtin_amdgcn_mfma_f32_16x16x32_bf16(al, bh, acc[nt], 0, 0, 0);
    }
  }
  float sqp[4] = {0.f, 0.f, 0.f, 0.f};
  #pragma unroll
  for (int nt = 0; nt < 8; nt++) {
    int col = colbase + nt*16 + m;
    float bp = mb[col];
    #pragma unroll
    for (int r = 0; r < 4; r++) {
      float o = fmaxf(acc[nt][r] + bp, 0.f);
      int row = rowbase + w*16 + quad*4 + r;
      unsigned short h = f2bf(o);
      xhi[(size_t)row*DD + col] = h;
      xlo[(size_t)row*DD + col] = f2bf(o - bf2f(h));
      sqp[r] += o*o;
    }
  }
  #pragma unroll
  for (int r = 0; r < 4; r++) {
    #pragma unroll
    for (int mm = 1; mm <= 8; mm <<= 1) sqp[r] += __shfl_xor(sqp[r], mm, 64);
  }
  if (m == 0) {
    #pragma unroll
    for (int r = 0; r < 4; r++)
      atomicAdd(&sqo[rowbase + w*16 + quad*4 + r], sqp[r]);
  }
}

// ---------------- u/v GEMM via split-bf16 MFMA, col-split + uv-split (R25-proven)
__global__ __launch_bounds__(256) void gemmuv(
    const unsigned short* __restrict__ xhi, const unsigned short* __restrict__ xlo,
    const unsigned short* __restrict__ Wuh, const unsigned short* __restrict__ Wul,
    const unsigned short* __restrict__ Wbh, const unsigned short* __restrict__ Wbl,
    float* __restrict__ U, float* __restrict__ V)
{
  __shared__ float wSh[128*18];
  __shared__ float wSl[128*18];
  int tid = threadIdx.x;
  int w = tid >> 6, lane = tid & 63;
  int m = lane & 15, quad = lane >> 4;
  int rowbase = blockIdx.x * 64;
  int uv = blockIdx.y >> 1;
  int colbase = (blockIdx.y & 1) * 128;
  const unsigned short* Wh = uv ? Wbh : Wuh;
  const unsigned short* Wl = uv ? Wbl : Wul;
  float* Out = uv ? V : U;
  size_t aoff = (size_t)(rowbase + w*16 + m)*DD;
  int srow = tid >> 1;
  int sseg = (tid & 1) * 2;
  f32x4 acc[8];
  #pragma unroll
  for (int t = 0; t < 8; t++) acc[t] = (f32x4){0.f, 0.f, 0.f, 0.f};
  #pragma unroll 1
  for (int c = 0; c < 8; c++) {
    int k0 = c*32 + quad*8;
    bf16x8 ah = *(const bf16x8*)(xhi + aoff + k0);
    bf16x8 al = *(const bf16x8*)(xlo + aoff + k0);
    const float* wrh = (const float*)(Wh + (size_t)(colbase + srow)*DD + c*32);
    const float* wrl = (const float*)(Wl + (size_t)(colbase + srow)*DD + c*32);
    float4 wh0 = *(const float4*)(wrh + sseg*4);
    float4 wh1 = *(const float4*)(wrh + (sseg+1)*4);
    float4 wl0 = *(const float4*)(wrl + sseg*4);
    float4 wl1 = *(const float4*)(wrl + (sseg+1)*4);
    __syncthreads();
    *(float4*)&wSh[srow*18 + sseg*4]     = wh0;
    *(float4*)&wSh[srow*18 + (sseg+1)*4] = wh1;
    *(float4*)&wSl[srow*18 + sseg*4]     = wl0;
    *(float4*)&wSl[srow*18 + (sseg+1)*4] = wl1;
    __syncthreads();
    #pragma unroll
    for (int nt = 0; nt < 8; nt++) {
      bf16x8 bh = *(const bf16x8*)&wSh[(nt*16 + m)*18 + quad*4];
      bf16x8 bl = *(const bf16x8*)&wSl[(nt*16 + m)*18 + quad*4];
      acc[nt] = __builtin_amdgcn_mfma_f32_16x16x32_bf16(ah, bh, acc[nt], 0, 0, 0);
      acc[nt] = __builtin_amdgcn_mfma_f32_16x16x32_bf16(ah, bl, acc[nt], 0, 0, 0);
      acc[nt] = __builtin_amdgcn_mfma_f32_16x16x32_bf16(al, bh, acc[nt], 0, 0, 0);
    }
  }
  #pragma unroll
  for (int nt = 0; nt < 8; nt++) {
    int col = colbase + nt*16 + m;
    #pragma unroll
    for (int r = 0; r < 4; r++) {
      int row = rowbase + w*16 + quad*4 + r;
      Out[(size_t)row*DD + col] = acc[nt][r];
    }
  }
}

// ---------------- kNN via split-bf16 MFMA, LDS-staged j-rows, register-hoisted A
// (R20/R23-proven). R29: partial-list spill padded to stride 9 (was stride 8 ->
// 8-way bank conflict, ~14k conflict-cycles/block).
__global__ __launch_bounds__(256) void knnk(
    const unsigned short* __restrict__ xhi, const unsigned short* __restrict__ xlo,
    const float* __restrict__ sq,
    float* __restrict__ pdg, int* __restrict__ pjg)
{
  __shared__ float smem[4736];
  float* jh = smem;                 // 64 rows x 36 floats
  float* jl = smem + 2304;
  float (*dt)[65] = (float(*)[65])smem;
  float* sqI = smem + 4608;
  float* sqJ = smem + 4672;
  int tid = threadIdx.x;
  int q  = blockIdx.x & 3;
  int it = (blockIdx.x >> 2) & 31;
  int bb = blockIdx.x >> 7;
  int ibase = it * 64;
  const unsigned short* xhb = xhi + (size_t)bb*NN*DD;
  const unsigned short* xlb = xlo + (size_t)bb*NN*DD;
  const float* sqb = sq + (size_t)bb*NN;
  int w = tid >> 6, lane = tid & 63;
  int m = lane & 15, quad = lane >> 4;
  int selrow = tid & 63, selseg = tid >> 6;
  size_t aoff = (size_t)(ibase + w*16 + m)*DD;
  int srow = tid >> 2;
  int sseg = tid & 3;
  bf16x8 ahr[8], alr[8];
  #pragma unroll
  for (int c = 0; c < 8; c++) {
    int k0 = c*32 + quad*8;
    ahr[c] = *(const bf16x8*)(xhb + aoff + k0);
    alr[c] = *(const bf16x8*)(xlb + aoff + k0);
  }
  float bd[8]; int bj[8];
  #pragma unroll
  for (int s = 0; s < 8; s++) { bd[s] = 3.4e38f; bj[s] = 0; }
  if (tid < 64) sqI[tid] = sqb[ibase + tid];
  #pragma unroll 1
  for (int jt = 0; jt < 8; jt++) {
    int jbase = q*512 + jt*64;
    if (tid < 64) sqJ[tid] = sqb[jbase + tid];
    f32x4 acc[4];
    #pragma unroll
    for (int t = 0; t < 4; t++) acc[t] = (f32x4){0.f, 0.f, 0.f, 0.f};
    #pragma unroll
    for (int c2 = 0; c2 < 4; c2++) {
      size_t gb = (size_t)(jbase + srow)*DD + c2*64;
      float4 h0 = *(const float4*)((const float*)(xhb + gb) + sseg*4);
      float4 h1 = *(const float4*)((const float*)(xhb + gb) + (sseg+4)*4);
      float4 l0 = *(const float4*)((const float*)(xlb + gb) + sseg*4);
      float4 l1 = *(const float4*)((const float*)(xlb + gb) + (sseg+4)*4);
      __syncthreads();
      *(float4*)&jh[srow*36 + sseg*4]     = h0;
      *(float4*)&jh[srow*36 + (sseg+4)*4] = h1;
      *(float4*)&jl[srow*36 + sseg*4]     = l0;
      *(float4*)&jl[srow*36 + (sseg+4)*4] = l1;
      __syncthreads();
      #pragma unroll
      for (int kk = 0; kk < 2; kk++) {
        bf16x8 ah = ahr[c2*2 + kk];
        bf16x8 al = alr[c2*2 + kk];
        int lofs = kk*16 + quad*4;
        #pragma unroll
        for (int nt = 0; nt < 4; nt++) {
          int r = nt*16 + m;
          bf16x8 bh = *(const bf16x8*)&jh[r*36 + lofs];
          bf16x8 bl = *(const bf16x8*)&jl[r*36 + lofs];
          acc[nt] = __builtin_amdgcn_mfma_f32_16x16x32_bf16(ah, bh, acc[nt], 0, 0, 0);
          acc[nt] = __builtin_amdgcn_mfma_f32_16x16x32_bf16(ah, bl, acc[nt], 0, 0, 0);
          acc[nt] = __builtin_amdgcn_mfma_f32_16x16x32_bf16(al, bh, acc[nt], 0, 0, 0);
        }
      }
    }
    __syncthreads();
    #pragma unroll
    for (int nt = 0; nt < 4; nt++) {
      int col = nt*16 + m;
      float sj = sqJ[col];
      #pragma unroll
      for (int r = 0; r < 4; r++) {
        int rowl = w*16 + quad*4 + r;
        dt[rowl][col] = sqI[rowl] + sj - 2.f*acc[nt][r];
      }
    }
    __syncthreads();
    int cb = selseg*16;
    #pragma unroll
    for (int s = 0; s < 16; s++) {
      float dv = dt[selrow][cb + s];
      if (dv < bd[7]) {
        bd[7] = dv; bj[7] = jbase + cb + s;
        #pragma unroll
        for (int t = 7; t >= 1; t--) {
          if (bd[t] < bd[t-1]) {
            float td = bd[t]; bd[t] = bd[t-1]; bd[t-1] = td;
            int   tj = bj[t]; bj[t] = bj[t-1]; bj[t-1] = tj;
          }
        }
      }
    }
  }
  __syncthreads();
  // partial-list spill: stride 9 (coprime to 32 banks -> conflict-free)
  float* pdl = &smem[0];            // 256 x 9 = 2304
  int*   pjl = (int*)&smem[2304];   // 256 x 9 = 2304
  #pragma unroll
  for (int s = 0; s < 8; s++) {
    pdl[tid*9 + s] = bd[s];
    pjl[tid*9 + s] = bj[s];
  }
  __syncthreads();
  if (tid < 64) {
    float md[8]; int mj[8];
    #pragma unroll
    for (int s = 0; s < 8; s++) { md[s] = 3.4e38f; mj[s] = 0; }
    #pragma unroll 1
    for (int g = 0; g < 4; g++) {
      int base = (g*64 + tid)*9;
      #pragma unroll
      for (int s = 0; s < 8; s++) {
        float dv = pdl[base + s];
        if (dv < md[7]) {
          md[7] = dv; mj[7] = pjl[base + s];
          #pragma unroll
          for (int t = 7; t >= 1; t--) {
            if (md[t] < md[t-1]) {
              float td = md[t]; md[t] = md[t-1]; md[t-1] = td;
              int   tj = mj[t]; mj[t] = mj[t-1]; mj[t-1] = tj;
            }
          }
        }
      }
    }
    size_t gbase = ((size_t)(bb*NN + ibase + tid))*32 + (size_t)q*8;
    #pragma unroll
    for (int s = 0; s < 8; s++) {
      pdg[gbase + s] = md[s];
      pjg[gbase + s] = bb*NN + mj[s];
    }
  }
}

// ---------------- BN1 stats + fused kNN quarter-list merge.
// First 16 lanes merge the 4 quarter-lists for this block's 16 points (same scan
// order as the old knnmerge -> bit-identical idxg), write idxg for edgek + jL for
// local use; then the R28-proven float4 stats accumulation.
__global__ __launch_bounds__(256) void bn1stats(const float* __restrict__ u, const float* __restrict__ v,
    const float* __restrict__ pdg, const int* __restrict__ pjg,
    int* __restrict__ idxg, const float* __restrict__ b1, float* __restrict__ stats)
{
  __shared__ int jL[128];
  __shared__ float redS[4][256];
  __shared__ float redQ[4][256];
  int tid = threadIdx.x;
  int n0 = blockIdx.x * 16;
  if (tid < 16) {
    int p = n0 + tid;
    float md[8]; int mj[8];
    #pragma unroll
    for (int s = 0; s < 8; s++) { md[s] = 3.4e38f; mj[s] = 0; }
    size_t base = (size_t)p*32;
    #pragma unroll 1
    for (int s = 0; s < 32; s++) {
      float dv = pdg[base + s];
      if (dv < md[7]) {
        md[7] = dv; mj[7] = pjg[base + s];
        #pragma unroll
        for (int t = 7; t >= 1; t--) {
          if (md[t] < md[t-1]) {
            float td = md[t]; md[t] = md[t-1]; md[t-1] = td;
            int   tj = mj[t]; mj[t] = mj[t-1]; mj[t-1] = tj;
          }
        }
      }
    }
    #pragma unroll
    for (int s = 0; s < 8; s++) {
      jL[tid*8 + s] = mj[s];
      idxg[(size_t)p*8 + s] = mj[s];
    }
  }
  __syncthreads();
  int g = tid >> 6;               // point-group 0..3
  int cq = (tid & 63) * 4;        // channel quad base
  float4 b4 = *(const float4*)&b1[cq];
  float4 s = make_float4(0.f, 0.f, 0.f, 0.f);
  float4 q = make_float4(0.f, 0.f, 0.f, 0.f);
  #pragma unroll 1
  for (int n = 0; n < 4; n++) {
    int pl = g*4 + n;
    float4 u4 = *(const float4*)&u[(size_t)(n0 + pl)*DD + cq];
    float4 ub = make_float4(u4.x + b4.x, u4.y + b4.y, u4.z + b4.z, u4.w + b4.w);
    #pragma unroll
    for (int e = 0; e < 8; e++) {
      int j = jL[pl*8 + e];
      float4 v4 = *(const float4*)&v[(size_t)j*DD + cq];
      float h0 = fmaxf(ub.x + v4.x, 0.f);
      float h1 = fmaxf(ub.y + v4.y, 0.f);
      float h2 = fmaxf(ub.z + v4.z, 0.f);
      float h3 = fmaxf(ub.w + v4.w, 0.f);
      s.x += h0; s.y += h1; s.z += h2; s.w += h3;
      q.x += h0*h0; q.y += h1*h1; q.z += h2*h2; q.w += h3*h3;
    }
  }
  *(float4*)&redS[g][cq] = s;
  *(float4*)&redQ[g][cq] = q;
  __syncthreads();
  int c = tid;
  float ts = redS[0][c] + redS[1][c] + redS[2][c] + redS[3][c];
  float tq = redQ[0][c] + redQ[1][c] + redQ[2][c] + redQ[3][c];
  int row = blockIdx.x & (NSH - 1);
  atomicAdd(&stats[row*1024 + c], ts);
  atomicAdd(&stats[row*1024 + 256 + c], tq);
}

// ---------------- fold BN1 into layer-2 weights; emit TRANSPOSED bf16 weights
__global__ __launch_bounds__(256) void prep2(const float* __restrict__ stats, const float* __restrict__ g1,
    const float* __restrict__ be1, const float* __restrict__ gW2, const float* __restrict__ gb2,
    unsigned short* __restrict__ w2bf, float* __restrict__ biasp)
{
  __shared__ float s1L[256], t1L[256];
  int tid = threadIdx.x;
  const float inv = 1.f / (float)NEDGE;
  float sm = 0.f, sq2 = 0.f;
  #pragma unroll 1
  for (int r = 0; r < NSH; r++) {
    sm  += stats[r*1024 + tid];
    sq2 += stats[r*1024 + 256 + tid];
  }
  float m = sm * inv;
  float var = sq2*inv - m*m;
  float s1 = g1[tid] / sqrtf(var + BN_EPS);
  s1L[tid] = s1; t1L[tid] = be1[tid] - m*s1;
  __syncthreads();
  float bacc = gb2[tid];
  for (int k = 0; k < DD; k++) {
    float w = gW2[k*DD + tid];
    w2bf[(size_t)tid*DD + k] = f2bf(s1L[k]*w);
    bacc += t1L[k]*w;
  }
  biasp[tid] = bacc;
}

// ---------------- edge GEMM: col-split x2 + LDS-staged u-rows (R28-proven)
__global__ __launch_bounds__(256) void edgek(
    const float* __restrict__ u, const float* __restrict__ v, const int* __restrict__ idxg,
    const float* __restrict__ b1, const unsigned short* __restrict__ w2bf,
    const float* __restrict__ biasp,
    float* __restrict__ pmaxs, float* __restrict__ pmins, float* __restrict__ stats)
{
  __shared__ float wS[128*18];     // 9 KB
  __shared__ float uB[8*256];      // 8 KB: u-rows + b1
  int tid = threadIdx.x;
  int w = tid >> 6, lane = tid & 63;
  int m = lane & 15, quad = lane >> 4;
  int rowbase = blockIdx.x * 64;
  int colbase = blockIdx.y * 128;
  {
    int r = tid >> 5;              // 0..7
    int cc = (tid & 31) * 8;       // 0..248
    const float* ur = u + ((size_t)(rowbase >> 3) + r)*DD + cc;
    float4 a0 = *(const float4*)ur;
    float4 a1 = *(const float4*)(ur + 4);
    float4 b0 = *(const float4*)(b1 + cc);
    float4 b1v = *(const float4*)(b1 + cc + 4);
    *(float4*)&uB[r*256 + cc]     = make_float4(a0.x+b0.x, a0.y+b0.y, a0.z+b0.z, a0.w+b0.w);
    *(float4*)&uB[r*256 + cc + 4] = make_float4(a1.x+b1v.x, a1.y+b1v.y, a1.z+b1v.z, a1.w+b1v.w);
  }
  int edge = rowbase + w*16 + m;
  int iul = (w*16 + m) >> 3;       // local u-row 0..7
  int jv = idxg[edge];
  const float* vrow = v + (size_t)jv*DD;
  int srow = tid >> 1;
  int sseg = (tid & 1) * 2;
  f32x4 acc[8];
  #pragma unroll
  for (int t = 0; t < 8; t++) acc[t] = (f32x4){0.f, 0.f, 0.f, 0.f};
  __syncthreads();                 // uB visible
  #pragma unroll 1
  for (int c = 0; c < 8; c++) {
    int k0 = c*32 + quad*8;
    float4 va = *(const float4*)(vrow + k0);
    float4 vb = *(const float4*)(vrow + k0 + 4);
    float4 ua = *(const float4*)&uB[iul*256 + k0];
    float4 ub = *(const float4*)&uB[iul*256 + k0 + 4];
    const float* wrow = (const float*)(w2bf + (size_t)(colbase + srow)*DD + c*32);
    float4 wreg0 = *(const float4*)(wrow + sseg*4);
    float4 wreg1 = *(const float4*)(wrow + (sseg+1)*4);
    float h0 = fmaxf(ua.x+va.x, 0.f);
    float h1 = fmaxf(ua.y+va.y, 0.f);
    float h2 = fmaxf(ua.z+va.z, 0.f);
    float h3 = fmaxf(ua.w+va.w, 0.f);
    float h4 = fmaxf(ub.x+vb.x, 0.f);
    float h5 = fmaxf(ub.y+vb.y, 0.f);
    float h6 = fmaxf(ub.z+vb.z, 0.f);
    float h7 = fmaxf(ub.w+vb.w, 0.f);
    union { bf16x8 v8; unsigned short s[8]; } af;
    af.s[0] = f2bf(h0); af.s[1] = f2bf(h1); af.s[2] = f2bf(h2); af.s[3] = f2bf(h3);
    af.s[4] = f2bf(h4); af.s[5] = f2bf(h5); af.s[6] = f2bf(h6); af.s[7] = f2bf(h7);
    __syncthreads();
    *(float4*)&wS[srow*18 + sseg*4]     = wreg0;
    *(float4*)&wS[srow*18 + (sseg+1)*4] = wreg1;
    __syncthreads();
    #pragma unroll
    for (int nt = 0; nt < 8; nt++) {
      bf16x8 bf = *(const bf16x8*)&wS[(nt*16 + m)*18 + quad*4];
      acc[nt] = __builtin_amdgcn_mfma_f32_16x16x32_bf16(af.v8, bf, acc[nt], 0, 0, 0);
    }
  }
  float* redS = wS;
  float* redQ = wS + 512;
  float* redM = wS + 1024;
  float* redN = wS + 1536;
  float mxr[8], mnr[8], ssr[8], sqr[8];
  #pragma unroll
  for (int nt = 0; nt < 8; nt++) {
    int col = nt*16 + m;
    float bp = biasp[colbase + col];
    float r0 = fmaxf(acc[nt].x + bp, 0.f);
    float r1 = fmaxf(acc[nt].y + bp, 0.f);
    float r2 = fmaxf(acc[nt].z + bp, 0.f);
    float r3 = fmaxf(acc[nt].w + bp, 0.f);
    float mx = fmaxf(fmaxf(r0, r1), fmaxf(r2, r3));
    float mn = fminf(fminf(r0, r1), fminf(r2, r3));
    float ss = r0 + r1 + r2 + r3;
    float s2 = r0*r0 + r1*r1 + r2*r2 + r3*r3;
    mx = fmaxf(mx, __shfl_xor(mx, 16, 64));
    mx = fmaxf(mx, __shfl_xor(mx, 32, 64));
    mn = fminf(mn, __shfl_xor(mn, 16, 64));
    mn = fminf(mn, __shfl_xor(mn, 32, 64));
    ss += __shfl_xor(ss, 16, 64);
    ss += __shfl_xor(ss, 32, 64);
    s2 += __shfl_xor(s2, 16, 64);
    s2 += __shfl_xor(s2, 32, 64);
    mxr[nt] = mx; mnr[nt] = mn; ssr[nt] = ss; sqr[nt] = s2;
  }
  __syncthreads();
  if (quad == 0) {
    #pragma unroll
    for (int nt = 0; nt < 8; nt++) {
      int col = nt*16 + m;
      redS[w*128 + col] = ssr[nt];
      redQ[w*128 + col] = sqr[nt];
      redM[w*128 + col] = mxr[nt];
      redN[w*128 + col] = mnr[nt];
    }
  }
  __syncthreads();
  if (tid < 128) {
    float ts  = redS[tid] + redS[128+tid] + redS[256+tid] + redS[384+tid];
    float tq  = redQ[tid] + redQ[128+tid] + redQ[256+tid] + redQ[384+tid];
    float mxc = fmaxf(fmaxf(redM[tid], redM[128+tid]), fmaxf(redM[256+tid], redM[384+tid]));
    float mnc = fminf(fminf(redN[tid], redN[128+tid]), fminf(redN[256+tid], redN[384+tid]));
    int row = blockIdx.x & (NSH - 1);
    atomicAdd(&stats[row*1024 + 512 + colbase + tid], ts);
    atomicAdd(&stats[row*1024 + 768 + colbase + tid], tq);
    int b  = blockIdx.x >> 8;
    int sh = blockIdx.x & (PSH - 1);
    atomicMax((int*)&pmaxs[((size_t)sh*BB + b)*DD + colbase + tid], __float_as_int(mxc));
    atomicMin((int*)&pmins[((size_t)sh*BB + b)*DD + colbase + tid], __float_as_int(mnc));
  }
}

// ---------------- final: one block per batch (R18-proven)
__global__ __launch_bounds__(256) void finalk(const float* __restrict__ pmaxs, const float* __restrict__ pmins,
    const float* __restrict__ stats, const float* __restrict__ g2, const float* __restrict__ be2,
    const float* __restrict__ W1, const float* __restrict__ b1,
    const float* __restrict__ W2, const float* __restrict__ b2,
    float* __restrict__ out)
{
  __shared__ float pl[256];
  __shared__ float hl[256];
  __shared__ float red[4];
  int c = threadIdx.x;
  int b = blockIdx.x;
  const float inv = 1.f / (float)NEDGE;
  float sm = 0.f, sq2 = 0.f;
  #pragma unroll 1
  for (int r = 0; r < NSH; r++) {
    sm  += stats[r*1024 + 512 + c];
    sq2 += stats[r*1024 + 768 + c];
  }
  float m = sm * inv;
  float var = sq2*inv - m*m;
  float s2 = g2[c] / sqrtf(var + BN_EPS);
  float t2 = be2[c] - m*s2;
  float mx = -3.4e38f, mn = 3.4e38f;
  #pragma unroll 1
  for (int s = 0; s < PSH; s++) {
    mx = fmaxf(mx, pmaxs[((size_t)s*BB + b)*DD + c]);
    mn = fminf(mn, pmins[((size_t)s*BB + b)*DD + c]);
  }
  pl[c] = (s2 >= 0.f) ? s2*mx + t2 : s2*mn + t2;
  __syncthreads();
  float h = b1[c];
  #pragma unroll 4
  for (int k = 0; k < 256; k++) h += pl[k]*W1[k*256 + c];
  hl[c] = fmaxf(h, 0.f);
  __syncthreads();
  float o = b2[c];
  #pragma unroll 4
  for (int k = 0; k < 256; k++) o += hl[k]*W2[k*256 + c];
  o = fmaxf(o, 0.f);
  float s = o*o;
  #pragma unroll
  for (int mm = 1; mm <= 32; mm <<= 1) s += __shfl_xor(s, mm, 64);
  if ((c & 63) == 0) red[c >> 6] = s;
  __syncthreads();
  float tot = red[0] + red[1] + red[2] + red[3];
  out[b*256 + c] = o / fmaxf(sqrtf(tot), 1e-12f);
}

extern "C" void kernel_launch(void* const* d_in, const int* in_sizes, int n_in,
                              void* d_out, int out_size, void* d_ws, size_t ws_size,
                              hipStream_t stream) {
  (void)in_sizes; (void)n_in; (void)out_size; (void)ws_size;
  const int*   cls       = (const int*)  d_in[0];
  const float* colors    = (const float*)d_in[1];
  const float* positions = (const float*)d_in[2];
  const float* ctab      = (const float*)d_in[3];
  const float* pW1 = (const float*)d_in[4];
  const float* pb1 = (const float*)d_in[5];
  const float* pW2 = (const float*)d_in[6];
  const float* pb2 = (const float*)d_in[7];
  const float* cW1 = (const float*)d_in[8];
  const float* cb1 = (const float*)d_in[9];
  const float* cW2 = (const float*)d_in[10];
  const float* cb2 = (const float*)d_in[11];
  const float* mW  = (const float*)d_in[12];
  const float* mb  = (const float*)d_in[13];
  const float* gW1 = (const float*)d_in[14];
  const float* gb1 = (const float*)d_in[15];
  const float* gg1 = (const float*)d_in[16];
  const float* gbe1= (const float*)d_in[17];
  const float* gW2 = (const float*)d_in[18];
  const float* gb2 = (const float*)d_in[19];
  const float* gg2 = (const float*)d_in[20];
  const float* gbe2= (const float*)d_in[21];
  const float* lW1 = (const float*)d_in[22];
  const float* lb1 = (const float*)d_in[23];
  const float* lW2 = (const float*)d_in[24];
  const float* lb2 = (const float*)d_in[25];
  float* out = (float*)d_out;

  float* wsf   = (float*)d_ws;
  unsigned short* feathi = (unsigned short*)(wsf + OFF_FEAT);
  unsigned short* featlo = feathi + (size_t)NPTS*768;
  float* sq    = wsf + OFF_SQ;
  int*   idxg  = (int*)(wsf + OFF_IDX);
  float* u     = wsf + OFF_U;
  float* v     = wsf + OFF_V;
  unsigned short* w2bf = (unsigned short*)(wsf + OFF_W2BF);
  float* biasp = wsf + OFF_BIASP;
  unsigned short* xhi = (unsigned short*)(wsf + OFF_XHI);
  unsigned short* xlo = (unsigned short*)(wsf + OFF_XLO);
  unsigned short* mwh = (unsigned short*)(wsf + OFF_MWH);
  unsigned short* mwl = (unsigned short*)(wsf + OFF_MWL);
  unsigned short* Wuh = (unsigned short*)(wsf + OFF_WUH);
  unsigned short* Wul = (unsigned short*)(wsf + OFF_WUL);
  unsigned short* Wbh = (unsigned short*)(wsf + OFF_WBH);
  unsigned short* Wbl = (unsigned short*)(wsf + OFF_WBL);
  float* stats = wsf + OFF_STATS;
  float* pmaxs = wsf + OFF_PMAXS;
  float* pmins = wsf + OFF_PMINS;
  // partial kNN buffers overlay feathi/featlo region (dead after gemm768)
  float* pdg   = wsf + OFF_FEAT;
  int*   pjg   = (int*)(wsf + OFF_FEAT + (size_t)NPTS*32);

  // stats + pmaxs + sq are contiguous -> one zero memset
  hipMemsetAsync(stats, 0, (NSH*1024 + PSH*BB*DD + NPTS)*sizeof(float), stream);
  hipMemsetAsync(pmins, 0x7f, PSH*BB*DD*sizeof(float), stream);   // ~3.39e38f

  prepk<<<4096 + 768 + 256, 256, 0, stream>>>(cls, colors, positions, ctab,
                                              pW1, pb1, pW2, pb2, cW1, cb1, cW2, cb2,
                                              feathi, featlo, mW, mwh, mwl,
                                              gW1, Wuh, Wul, Wbh, Wbl);
  gemm768<<<dim3(NPTS/64, 2), 256, 0, stream>>>(feathi, featlo, mwh, mwl, mb, sq, xhi, xlo);
  knnk<<<BB*32*4, 256, 0, stream>>>(xhi, xlo, sq, pdg, pjg);
  gemmuv<<<dim3(NPTS/64, 4), 256, 0, stream>>>(xhi, xlo, Wuh, Wul, Wbh, Wbl, u, v);
  bn1stats<<<NPTS/16, 256, 0, stream>>>(u, v, pdg, pjg, idxg, gb1, stats);
  prep2<<<1, 256, 0, stream>>>(stats, gg1, gbe1, gW2, gb2, w2bf, biasp);
  edgek<<<dim3(NEDGE/64, 2), 256, 0, stream>>>(u, v, idxg, gb1, w2bf, biasp, pmaxs, pmins, stats);
  finalk<<<BB, 256, 0, stream>>>(pmaxs, pmins, stats, gg2, gbe2, lW1, lb1, lW2, lb2, out);
}